// Round 1
// baseline (1598.823 us; speedup 1.0000x reference)
//
#include <hip/hip_runtime.h>
#include <stdint.h>

#define D    128
#define ED   5
#define K1E  261          // 2*D + ED
#define K1E4 66           // ceil(261/4)
#define KU   256          // update in-dim
#define BLK  512
#define WPB  8            // waves per block
#define GRID 256

__device__ __forceinline__ float wred_sum(float v) {
    v += __shfl_xor(v, 32, 64);
    v += __shfl_xor(v, 16, 64);
    v += __shfl_xor(v, 8, 64);
    v += __shfl_xor(v, 4, 64);
    v += __shfl_xor(v, 2, 64);
    v += __shfl_xor(v, 1, 64);
    return v;
}

__device__ __forceinline__ unsigned short f2bf(float f) {
    union { float f; uint32_t u; } c; c.f = f;
    uint32_t r = (c.u + 0x7fffu + ((c.u >> 16) & 1u)) >> 16;
    return (unsigned short)r;
}
__device__ __forceinline__ float bflo(uint32_t u) {
    union { uint32_t u; float f; } c; c.u = u << 16; return c.f;
}
__device__ __forceinline__ float bfhi(uint32_t u) {
    union { uint32_t u; float f; } c; c.u = u & 0xffff0000u; return c.f;
}

// ---------------- node MLP: hn = relu(LN(x@W1+b1))@W2+b2 ----------------
__global__ __launch_bounds__(BLK, 1)
void node_kernel(const float* __restrict__ x,
                 const float* __restrict__ w1, const float* __restrict__ b1,
                 const float* __restrict__ g1, const float* __restrict__ be1,
                 const float* __restrict__ w2, const float* __restrict__ b2,
                 float* __restrict__ hn, int N)
{
    __shared__ float4 w1p[D / 4][D];                  // w1p[k4][c][j] = w1[4k4+j][c]
    __shared__ float4 w2p[D / 4][D];
    __shared__ __align__(16) float xld[WPB][2][D];
    __shared__ __align__(16) float yld[WPB][2][D];

    const int tid = threadIdx.x;
    for (int i = tid; i < D * D; i += BLK) {
        int k = i / D, c = i - k * D;
        ((float*)&w1p[k >> 2][c])[k & 3] = w1[i];
        ((float*)&w2p[k >> 2][c])[k & 3] = w2[i];
    }
    __syncthreads();

    const int wave = tid >> 6, lane = tid & 63;
    const int c0 = lane, c1 = lane + 64;
    const float B1a = b1[c0], B1b = b1[c1], G1a = g1[c0], G1b = g1[c1];
    const float E1a = be1[c0], E1b = be1[c1], B2a = b2[c0], B2b = b2[c1];

    const int gw = blockIdx.x * WPB + wave;
    const int nW = gridDim.x * WPB;
    const int nPairs = (N + 1) >> 1;
    const int nIter = (nPairs + nW - 1) / nW;

    for (int it = 0; it < nIter; ++it) {
        const int p = gw + it * nW;
        const bool act = p < nPairs;
        const int r0 = act ? (p << 1) : 0;
        const int r1 = (r0 + 1 < N) ? (r0 + 1) : r0;

        float2 va = *(const float2*)&x[(size_t)r0 * D + 2 * lane];
        float2 vb = *(const float2*)&x[(size_t)r1 * D + 2 * lane];
        xld[wave][0][2 * lane] = va.x; xld[wave][0][2 * lane + 1] = va.y;
        xld[wave][1][2 * lane] = vb.x; xld[wave][1][2 * lane + 1] = vb.y;
        __syncthreads();

        float a00 = 0.f, a01 = 0.f, a10 = 0.f, a11 = 0.f;
        #pragma unroll 8
        for (int k4 = 0; k4 < D / 4; ++k4) {
            const float4 wa = w1p[k4][c0];
            const float4 wb = w1p[k4][c1];
            const float4 f0 = *(const float4*)&xld[wave][0][4 * k4];
            const float4 f1 = *(const float4*)&xld[wave][1][4 * k4];
            a00 += f0.x * wa.x; a00 += f0.y * wa.y; a00 += f0.z * wa.z; a00 += f0.w * wa.w;
            a01 += f0.x * wb.x; a01 += f0.y * wb.y; a01 += f0.z * wb.z; a01 += f0.w * wb.w;
            a10 += f1.x * wa.x; a10 += f1.y * wa.y; a10 += f1.z * wa.z; a10 += f1.w * wa.w;
            a11 += f1.x * wb.x; a11 += f1.y * wb.y; a11 += f1.z * wb.z; a11 += f1.w * wb.w;
        }
        a00 += B1a; a01 += B1b; a10 += B1a; a11 += B1b;
        float m0 = wred_sum(a00 + a01) * (1.f / D);
        float q0 = wred_sum(a00 * a00 + a01 * a01) * (1.f / D);
        float m1 = wred_sum(a10 + a11) * (1.f / D);
        float q1 = wred_sum(a10 * a10 + a11 * a11) * (1.f / D);
        float rs0 = rsqrtf(q0 - m0 * m0 + 1e-5f);
        float rs1 = rsqrtf(q1 - m1 * m1 + 1e-5f);
        yld[wave][0][c0] = fmaxf((a00 - m0) * rs0 * G1a + E1a, 0.f);
        yld[wave][0][c1] = fmaxf((a01 - m0) * rs0 * G1b + E1b, 0.f);
        yld[wave][1][c0] = fmaxf((a10 - m1) * rs1 * G1a + E1a, 0.f);
        yld[wave][1][c1] = fmaxf((a11 - m1) * rs1 * G1b + E1b, 0.f);
        __syncthreads();

        float o00 = 0.f, o01 = 0.f, o10 = 0.f, o11 = 0.f;
        #pragma unroll 8
        for (int k4 = 0; k4 < D / 4; ++k4) {
            const float4 wa = w2p[k4][c0];
            const float4 wb = w2p[k4][c1];
            const float4 f0 = *(const float4*)&yld[wave][0][4 * k4];
            const float4 f1 = *(const float4*)&yld[wave][1][4 * k4];
            o00 += f0.x * wa.x; o00 += f0.y * wa.y; o00 += f0.z * wa.z; o00 += f0.w * wa.w;
            o01 += f0.x * wb.x; o01 += f0.y * wb.y; o01 += f0.z * wb.z; o01 += f0.w * wb.w;
            o10 += f1.x * wa.x; o10 += f1.y * wa.y; o10 += f1.z * wa.z; o10 += f1.w * wa.w;
            o11 += f1.x * wb.x; o11 += f1.y * wb.y; o11 += f1.z * wb.z; o11 += f1.w * wb.w;
        }
        if (act) {
            hn[(size_t)r0 * D + c0] = o00 + B2a;
            hn[(size_t)r0 * D + c1] = o01 + B2b;
            hn[(size_t)r1 * D + c0] = o10 + B2a;
            hn[(size_t)r1 * D + c1] = o11 + B2b;
        }
    }
}

// ---- edge MLP + scatter: agg[dst] += relu(LN(ef@W1+b1))@W2+b2 ----
__global__ __launch_bounds__(BLK, 1)
void edge_kernel(const float* __restrict__ x, const float* __restrict__ ea,
                 const int* __restrict__ ei,
                 const float* __restrict__ w1, const float* __restrict__ b1,
                 const float* __restrict__ g1, const float* __restrict__ be1,
                 const float* __restrict__ w2, const float* __restrict__ b2,
                 float* __restrict__ agg, int E)
{
    __shared__ uint2 w1p[K1E4][D];                        // bf16x4 along k
    __shared__ uint2 w2p[D / 4][D];
    __shared__ __align__(16) float efld[WPB][2][K1E4 * 4];
    __shared__ __align__(16) float tld[WPB][2][D];

    const int tid = threadIdx.x;
    for (int i = tid; i < K1E4 * 4 * D; i += BLK) {
        int k = i / D, c = i - k * D;
        float v = (k < K1E) ? w1[k * D + c] : 0.f;
        ((unsigned short*)&w1p[k >> 2][c])[k & 3] = f2bf(v);
    }
    for (int i = tid; i < D * D; i += BLK) {
        int k = i / D, c = i - k * D;
        ((unsigned short*)&w2p[k >> 2][c])[k & 3] = f2bf(w2[k * D + c]);
    }
    __syncthreads();

    // int64-vs-int32 edge_index hedge: int64 node ids < 2^31 have zero high words.
    const bool is64 = (ei[1] == 0) & (ei[3] == 0) & (ei[5] == 0) &
                      (ei[7] == 0) & (ei[9] == 0) & (ei[11] == 0);

    const int wave = tid >> 6, lane = tid & 63;
    const int c0 = lane, c1 = lane + 64;
    const float B1a = b1[c0], B1b = b1[c1], G1a = g1[c0], G1b = g1[c1];
    const float E1a = be1[c0], E1b = be1[c1], B2a = b2[c0], B2b = b2[c1];

    const int gw = blockIdx.x * WPB + wave;
    const int nW = gridDim.x * WPB;
    const int nPairs = (E + 1) >> 1;
    const int nIter = (nPairs + nW - 1) / nW;

    for (int it = 0; it < nIter; ++it) {
        const int p = gw + it * nW;
        const bool act = p < nPairs;
        const int e0 = act ? (p << 1) : 0;
        const bool has2 = act && (e0 + 1 < E);
        const int e1 = (e0 + 1 < E) ? (e0 + 1) : e0;

        int s0, d0, s1, d1;
        if (is64) {
            s0 = ei[2 * e0];       d0 = ei[2 * (E + e0)];
            s1 = ei[2 * e1];       d1 = ei[2 * (E + e1)];
        } else {
            s0 = ei[e0];           d0 = ei[E + e0];
            s1 = ei[e1];           d1 = ei[E + e1];
        }

        {
            float2 v;
            v = *(const float2*)&x[(size_t)s0 * D + 2 * lane];
            efld[wave][0][2 * lane] = v.x;     efld[wave][0][2 * lane + 1] = v.y;
            v = *(const float2*)&x[(size_t)d0 * D + 2 * lane];
            efld[wave][0][D + 2 * lane] = v.x; efld[wave][0][D + 2 * lane + 1] = v.y;
            v = *(const float2*)&x[(size_t)s1 * D + 2 * lane];
            efld[wave][1][2 * lane] = v.x;     efld[wave][1][2 * lane + 1] = v.y;
            v = *(const float2*)&x[(size_t)d1 * D + 2 * lane];
            efld[wave][1][D + 2 * lane] = v.x; efld[wave][1][D + 2 * lane + 1] = v.y;
            if (lane < 8) {
                efld[wave][0][2 * D + lane] = (lane < ED) ? ea[(size_t)e0 * ED + lane] : 0.f;
                efld[wave][1][2 * D + lane] = (lane < ED) ? ea[(size_t)e1 * ED + lane] : 0.f;
            }
        }
        __syncthreads();

        float a00 = 0.f, a01 = 0.f, a10 = 0.f, a11 = 0.f;
        #pragma unroll 4
        for (int k4 = 0; k4 < K1E4; ++k4) {
            const uint2 wa = w1p[k4][c0];
            const uint2 wb = w1p[k4][c1];
            const float4 f0 = *(const float4*)&efld[wave][0][4 * k4];
            const float4 f1 = *(const float4*)&efld[wave][1][4 * k4];
            const float wa0 = bflo(wa.x), wa1 = bfhi(wa.x), wa2 = bflo(wa.y), wa3 = bfhi(wa.y);
            const float wb0 = bflo(wb.x), wb1 = bfhi(wb.x), wb2 = bflo(wb.y), wb3 = bfhi(wb.y);
            a00 += f0.x * wa0; a00 += f0.y * wa1; a00 += f0.z * wa2; a00 += f0.w * wa3;
            a01 += f0.x * wb0; a01 += f0.y * wb1; a01 += f0.z * wb2; a01 += f0.w * wb3;
            a10 += f1.x * wa0; a10 += f1.y * wa1; a10 += f1.z * wa2; a10 += f1.w * wa3;
            a11 += f1.x * wb0; a11 += f1.y * wb1; a11 += f1.z * wb2; a11 += f1.w * wb3;
        }
        a00 += B1a; a01 += B1b; a10 += B1a; a11 += B1b;
        float m0 = wred_sum(a00 + a01) * (1.f / D);
        float q0 = wred_sum(a00 * a00 + a01 * a01) * (1.f / D);
        float m1 = wred_sum(a10 + a11) * (1.f / D);
        float q1 = wred_sum(a10 * a10 + a11 * a11) * (1.f / D);
        float rs0 = rsqrtf(q0 - m0 * m0 + 1e-5f);
        float rs1 = rsqrtf(q1 - m1 * m1 + 1e-5f);
        tld[wave][0][c0] = fmaxf((a00 - m0) * rs0 * G1a + E1a, 0.f);
        tld[wave][0][c1] = fmaxf((a01 - m0) * rs0 * G1b + E1b, 0.f);
        tld[wave][1][c0] = fmaxf((a10 - m1) * rs1 * G1a + E1a, 0.f);
        tld[wave][1][c1] = fmaxf((a11 - m1) * rs1 * G1b + E1b, 0.f);
        __syncthreads();

        float o00 = 0.f, o01 = 0.f, o10 = 0.f, o11 = 0.f;
        #pragma unroll 4
        for (int k4 = 0; k4 < D / 4; ++k4) {
            const uint2 wa = w2p[k4][c0];
            const uint2 wb = w2p[k4][c1];
            const float4 f0 = *(const float4*)&tld[wave][0][4 * k4];
            const float4 f1 = *(const float4*)&tld[wave][1][4 * k4];
            const float wa0 = bflo(wa.x), wa1 = bfhi(wa.x), wa2 = bflo(wa.y), wa3 = bfhi(wa.y);
            const float wb0 = bflo(wb.x), wb1 = bfhi(wb.x), wb2 = bflo(wb.y), wb3 = bfhi(wb.y);
            o00 += f0.x * wa0; o00 += f0.y * wa1; o00 += f0.z * wa2; o00 += f0.w * wa3;
            o01 += f0.x * wb0; o01 += f0.y * wb1; o01 += f0.z * wb2; o01 += f0.w * wb3;
            o10 += f1.x * wa0; o10 += f1.y * wa1; o10 += f1.z * wa2; o10 += f1.w * wa3;
            o11 += f1.x * wb0; o11 += f1.y * wb1; o11 += f1.z * wb2; o11 += f1.w * wb3;
        }
        if (act) {
            atomicAdd(&agg[(size_t)d0 * D + c0], o00 + B2a);
            atomicAdd(&agg[(size_t)d0 * D + c1], o01 + B2b);
            if (has2) {
                atomicAdd(&agg[(size_t)d1 * D + c0], o10 + B2a);
                atomicAdd(&agg[(size_t)d1 * D + c1], o11 + B2b);
            }
        }
    }
}

// ---- update: out = LN(concat(hn,agg)@uw + ub + x) ----
__global__ __launch_bounds__(BLK, 1)
void update_kernel(const float* __restrict__ x,
                   const float* __restrict__ hn, const float* __restrict__ agg,
                   const float* __restrict__ uw, const float* __restrict__ ub,
                   const float* __restrict__ lg, const float* __restrict__ lb,
                   float* __restrict__ out, int N)
{
    __shared__ float4 wp[KU / 4][D];                 // 128 KiB
    __shared__ __align__(16) float yld[WPB][2][KU];

    const int tid = threadIdx.x;
    for (int i = tid; i < KU * D; i += BLK) {
        int k = i / D, c = i - k * D;
        ((float*)&wp[k >> 2][c])[k & 3] = uw[i];
    }
    __syncthreads();

    const int wave = tid >> 6, lane = tid & 63;
    const int c0 = lane, c1 = lane + 64;
    const float UBa = ub[c0], UBb = ub[c1];
    const float Ga = lg[c0], Gb = lg[c1], Ba = lb[c0], Bb = lb[c1];

    const int gw = blockIdx.x * WPB + wave;
    const int nW = gridDim.x * WPB;
    const int nPairs = (N + 1) >> 1;
    const int nIter = (nPairs + nW - 1) / nW;

    for (int it = 0; it < nIter; ++it) {
        const int p = gw + it * nW;
        const bool act = p < nPairs;
        const int r0 = act ? (p << 1) : 0;
        const int r1 = (r0 + 1 < N) ? (r0 + 1) : r0;

        float2 v;
        v = *(const float2*)&hn[(size_t)r0 * D + 2 * lane];
        yld[wave][0][2 * lane] = v.x;     yld[wave][0][2 * lane + 1] = v.y;
        v = *(const float2*)&agg[(size_t)r0 * D + 2 * lane];
        yld[wave][0][D + 2 * lane] = v.x; yld[wave][0][D + 2 * lane + 1] = v.y;
        v = *(const float2*)&hn[(size_t)r1 * D + 2 * lane];
        yld[wave][1][2 * lane] = v.x;     yld[wave][1][2 * lane + 1] = v.y;
        v = *(const float2*)&agg[(size_t)r1 * D + 2 * lane];
        yld[wave][1][D + 2 * lane] = v.x; yld[wave][1][D + 2 * lane + 1] = v.y;
        __syncthreads();

        float a00 = 0.f, a01 = 0.f, a10 = 0.f, a11 = 0.f;
        #pragma unroll 8
        for (int k4 = 0; k4 < KU / 4; ++k4) {
            const float4 wa = wp[k4][c0];
            const float4 wb = wp[k4][c1];
            const float4 f0 = *(const float4*)&yld[wave][0][4 * k4];
            const float4 f1 = *(const float4*)&yld[wave][1][4 * k4];
            a00 += f0.x * wa.x; a00 += f0.y * wa.y; a00 += f0.z * wa.z; a00 += f0.w * wa.w;
            a01 += f0.x * wb.x; a01 += f0.y * wb.y; a01 += f0.z * wb.z; a01 += f0.w * wb.w;
            a10 += f1.x * wa.x; a10 += f1.y * wa.y; a10 += f1.z * wa.z; a10 += f1.w * wa.w;
            a11 += f1.x * wb.x; a11 += f1.y * wb.y; a11 += f1.z * wb.z; a11 += f1.w * wb.w;
        }
        float v00 = a00 + UBa + x[(size_t)r0 * D + c0];
        float v01 = a01 + UBb + x[(size_t)r0 * D + c1];
        float v10 = a10 + UBa + x[(size_t)r1 * D + c0];
        float v11 = a11 + UBb + x[(size_t)r1 * D + c1];
        float m0 = wred_sum(v00 + v01) * (1.f / D);
        float q0 = wred_sum(v00 * v00 + v01 * v01) * (1.f / D);
        float m1 = wred_sum(v10 + v11) * (1.f / D);
        float q1 = wred_sum(v10 * v10 + v11 * v11) * (1.f / D);
        float rs0 = rsqrtf(q0 - m0 * m0 + 1e-5f);
        float rs1 = rsqrtf(q1 - m1 * m1 + 1e-5f);
        if (act) {
            out[(size_t)r0 * D + c0] = (v00 - m0) * rs0 * Ga + Ba;
            out[(size_t)r0 * D + c1] = (v01 - m0) * rs0 * Gb + Bb;
            out[(size_t)r1 * D + c0] = (v10 - m1) * rs1 * Ga + Ba;
            out[(size_t)r1 * D + c1] = (v11 - m1) * rs1 * Gb + Bb;
        }
    }
}

extern "C" void kernel_launch(void* const* d_in, const int* in_sizes, int n_in,
                              void* d_out, int out_size, void* d_ws, size_t ws_size,
                              hipStream_t stream)
{
    const float* x    = (const float*)d_in[0];
    const float* ea   = (const float*)d_in[1];
    const float* nw1  = (const float*)d_in[3];
    const float* nb1  = (const float*)d_in[4];
    const float* ng1  = (const float*)d_in[5];
    const float* nbe1 = (const float*)d_in[6];
    const float* nw2  = (const float*)d_in[7];
    const float* nb2  = (const float*)d_in[8];
    const float* ew1  = (const float*)d_in[9];
    const float* eb1  = (const float*)d_in[10];
    const float* eg1  = (const float*)d_in[11];
    const float* ebe1 = (const float*)d_in[12];
    const float* ew2  = (const float*)d_in[13];
    const float* eb2  = (const float*)d_in[14];
    const float* uw   = (const float*)d_in[15];
    const float* ub   = (const float*)d_in[16];
    const float* lg   = (const float*)d_in[17];
    const float* lb   = (const float*)d_in[18];
    const int*   eidx = (const int*)d_in[19];

    const int N = in_sizes[0] / D;
    const int E = in_sizes[1] / ED;

    float* h_nodes = (float*)d_ws;
    float* h_agg   = h_nodes + (size_t)N * D;

    hipMemsetAsync(h_agg, 0, (size_t)N * D * sizeof(float), stream);
    node_kernel<<<GRID, BLK, 0, stream>>>(x, nw1, nb1, ng1, nbe1, nw2, nb2, h_nodes, N);
    edge_kernel<<<GRID, BLK, 0, stream>>>(x, ea, eidx, ew1, eb1, eg1, ebe1, ew2, eb2, h_agg, E);
    update_kernel<<<GRID, BLK, 0, stream>>>(x, h_nodes, h_agg, uw, ub, lg, lb, (float*)d_out, N);
}

// Round 2
// 650.616 us; speedup vs baseline: 2.4574x; 2.4574x over previous
//
#include <hip/hip_runtime.h>
#include <stdint.h>

#define D    128
#define ED   5
#define BLK  512
#define WPB  8
#define W1S  296   // u16 stride of W1^T rows (16B aligned, low-conflict)
#define W2S  136
#define HS   136
#define GRID 256

typedef __attribute__((ext_vector_type(8))) short bf16x8;
typedef __attribute__((ext_vector_type(4))) float f32x4;

__device__ __forceinline__ unsigned short f2bf(float f) {
    union { float f; uint32_t u; } c; c.f = f;
    uint32_t r = (c.u + 0x7fffu + ((c.u >> 16) & 1u)) >> 16;
    return (unsigned short)r;
}

__device__ __forceinline__ bf16x8 cvt8(const float* __restrict__ p) {
    float4 a = *(const float4*)p;
    float4 b = *(const float4*)(p + 4);
    bf16x8 r;
    r[0] = (short)f2bf(a.x); r[1] = (short)f2bf(a.y);
    r[2] = (short)f2bf(a.z); r[3] = (short)f2bf(a.w);
    r[4] = (short)f2bf(b.x); r[5] = (short)f2bf(b.y);
    r[6] = (short)f2bf(b.z); r[7] = (short)f2bf(b.w);
    return r;
}

__global__ __launch_bounds__(256, 4)
void cvt_x_kernel(const float* __restrict__ in, unsigned short* __restrict__ out, int n8) {
    int i = blockIdx.x * blockDim.x + threadIdx.x;
    if (i >= n8) return;
    float4 a = ((const float4*)in)[2 * i];
    float4 b = ((const float4*)in)[2 * i + 1];
    union { unsigned short s[8]; uint4 v; } p;
    p.s[0] = f2bf(a.x); p.s[1] = f2bf(a.y); p.s[2] = f2bf(a.z); p.s[3] = f2bf(a.w);
    p.s[4] = f2bf(b.x); p.s[5] = f2bf(b.y); p.s[6] = f2bf(b.z); p.s[7] = f2bf(b.w);
    ((uint4*)out)[i] = p.v;
}

// One wave = one 16-row m-tile. GEMM1 (K=288 edge / 128 node) -> LN+ReLU ->
// LDS h round-trip -> GEMM2 (K=128) -> atomic scatter (edge) / store (node).
template<bool EDGE, bool XBF>
__global__ __launch_bounds__(BLK, 1)
void mlp_kernel(const float* __restrict__ x, const unsigned short* __restrict__ xbf,
                const float* __restrict__ ea, const int* __restrict__ ei,
                const float* __restrict__ w1, const float* __restrict__ b1,
                const float* __restrict__ g1, const float* __restrict__ be1,
                const float* __restrict__ w2, const float* __restrict__ b2,
                float* __restrict__ outp, int N, int E)
{
    __shared__ unsigned short w1t[128 * W1S];   // W1^T bf16 [n][k]
    __shared__ unsigned short w2t[128 * W2S];   // W2^T bf16 [n][k]
    __shared__ unsigned short hb[WPB][16 * HS]; // per-wave h tile [m][col]

    const int tid = threadIdx.x;
    const int KROWS = EDGE ? 288 : 128;
    for (int i = tid; i < KROWS * 128; i += BLK) {
        int k = i >> 7, n = i & 127;
        float v = (!EDGE || k < (2 * D + ED)) ? w1[k * 128 + n] : 0.f;
        w1t[n * W1S + k] = f2bf(v);
    }
    for (int i = tid; i < 128 * 128; i += BLK) {
        int k = i >> 7, n = i & 127;
        w2t[n * W2S + k] = f2bf(w2[k * 128 + n]);
    }
    __syncthreads();

    bool is64 = false;
    if (EDGE)
        is64 = (ei[1] == 0) & (ei[3] == 0) & (ei[5] == 0) &
               (ei[7] == 0) & (ei[9] == 0) & (ei[11] == 0);

    const int lane = tid & 63, w = tid >> 6;
    const int g = lane >> 4, c = lane & 15;

    float b1v[8], g1v[8], e1v[8], b2v[8];
    #pragma unroll
    for (int nt = 0; nt < 8; ++nt) {
        b1v[nt] = b1[nt * 16 + c];  g1v[nt] = g1[nt * 16 + c];
        e1v[nt] = be1[nt * 16 + c]; b2v[nt] = b2[nt * 16 + c];
    }

    const int cnt = EDGE ? E : N;
    const int nT = (cnt + 15) >> 4;
    unsigned short* hw = hb[w];

    for (int tile = blockIdx.x * WPB + w; tile < nT; tile += gridDim.x * WPB) {
        const int row = tile * 16 + c;               // this lane's A-row (m = c)
        const int rc  = row < cnt ? row : cnt - 1;

        int dd = 0;
        size_t aoff = 0, boff = 0;
        if (EDGE) {
            int s = is64 ? ei[2 * (size_t)rc]       : ei[rc];
            dd    = is64 ? ei[2 * ((size_t)E + rc)] : ei[(size_t)E + rc];
            aoff = (size_t)s * D;
            boff = (size_t)dd * D;
        } else {
            aoff = (size_t)rc * D;
        }

        const f32x4 z = {0.f, 0.f, 0.f, 0.f};
        f32x4 acc[8] = {z, z, z, z, z, z, z, z};

        #pragma unroll
        for (int kk = 0; kk < (EDGE ? 9 : 4); ++kk) {
            bf16x8 af;
            if (!EDGE || kk < 4) {
                if (XBF) af = *(const bf16x8*)(xbf + aoff + kk * 32 + 8 * g);
                else     af = cvt8(x + aoff + kk * 32 + 8 * g);
            } else if (kk < 8) {
                if (XBF) af = *(const bf16x8*)(xbf + boff + (kk - 4) * 32 + 8 * g);
                else     af = cvt8(x + boff + (kk - 4) * 32 + 8 * g);
            } else {
                #pragma unroll
                for (int j = 0; j < 8; ++j) af[j] = 0;
                if (g == 0) {
                    #pragma unroll
                    for (int j = 0; j < ED; ++j)
                        af[j] = (short)f2bf(ea[(size_t)rc * ED + j]);
                }
            }
            const unsigned short* wr = &w1t[c * W1S + kk * 32 + 8 * g];
            #pragma unroll
            for (int nt = 0; nt < 8; ++nt) {
                bf16x8 bf = *(const bf16x8*)(wr + nt * 16 * W1S);
                acc[nt] = __builtin_amdgcn_mfma_f32_16x16x32_bf16(af, bf, acc[nt], 0, 0, 0);
            }
        }

        // bias + LayerNorm + ReLU; C layout: col = nt*16+c, row = 4g+r
        float mean[4], rstd[4];
        #pragma unroll
        for (int r = 0; r < 4; ++r) {
            float s = 0.f, q = 0.f;
            #pragma unroll
            for (int nt = 0; nt < 8; ++nt) {
                float v = acc[nt][r] + b1v[nt];
                acc[nt][r] = v;
                s += v; q += v * v;
            }
            s += __shfl_xor(s, 1, 64); q += __shfl_xor(q, 1, 64);
            s += __shfl_xor(s, 2, 64); q += __shfl_xor(q, 2, 64);
            s += __shfl_xor(s, 4, 64); q += __shfl_xor(q, 4, 64);
            s += __shfl_xor(s, 8, 64); q += __shfl_xor(q, 8, 64);
            float m = s * (1.f / 128.f);
            float var = q * (1.f / 128.f) - m * m;
            mean[r] = m;
            rstd[r] = rsqrtf(var + 1e-5f);
        }
        #pragma unroll
        for (int nt = 0; nt < 8; ++nt) {
            #pragma unroll
            for (int r = 0; r < 4; ++r) {
                float h = fmaxf((acc[nt][r] - mean[r]) * rstd[r] * g1v[nt] + e1v[nt], 0.f);
                hw[(4 * g + r) * HS + nt * 16 + c] = f2bf(h);
            }
        }
        // wave-private tile: same-wave DS ordering suffices, no barrier

        f32x4 acc2[8] = {z, z, z, z, z, z, z, z};
        #pragma unroll
        for (int kk = 0; kk < 4; ++kk) {
            bf16x8 af = *(const bf16x8*)&hw[c * HS + kk * 32 + 8 * g];
            const unsigned short* wr = &w2t[c * W2S + kk * 32 + 8 * g];
            #pragma unroll
            for (int nt = 0; nt < 8; ++nt) {
                bf16x8 bf = *(const bf16x8*)(wr + nt * 16 * W2S);
                acc2[nt] = __builtin_amdgcn_mfma_f32_16x16x32_bf16(af, bf, acc2[nt], 0, 0, 0);
            }
        }

        if (EDGE) {
            int dv[4];
            #pragma unroll
            for (int r = 0; r < 4; ++r) dv[r] = __shfl(dd, 4 * g + r, 64);
            #pragma unroll
            for (int r = 0; r < 4; ++r) {
                const int er = tile * 16 + 4 * g + r;
                if (er < cnt) {
                    float* dst = outp + (size_t)dv[r] * D + c;
                    #pragma unroll
                    for (int nt = 0; nt < 8; ++nt)
                        atomicAdd(dst + nt * 16, acc2[nt][r] + b2v[nt]);
                }
            }
        } else {
            #pragma unroll
            for (int r = 0; r < 4; ++r) {
                const int nr = tile * 16 + 4 * g + r;
                if (nr < cnt) {
                    float* dst = outp + (size_t)nr * D + c;
                    #pragma unroll
                    for (int nt = 0; nt < 8; ++nt)
                        dst[nt * 16] = acc2[nt][r] + b2v[nt];
                }
            }
        }
    }
}

// ---- update: out = LN(concat(hn,agg)@uw + ub + x)  (f32 VALU, unchanged) ----
#define KU 256
__global__ __launch_bounds__(BLK, 1)
void update_kernel(const float* __restrict__ x,
                   const float* __restrict__ hn, const float* __restrict__ agg,
                   const float* __restrict__ uw, const float* __restrict__ ub,
                   const float* __restrict__ lg, const float* __restrict__ lb,
                   float* __restrict__ out, int N)
{
    __shared__ float4 wp[KU / 4][D];
    __shared__ __align__(16) float yld[WPB][2][KU];

    const int tid = threadIdx.x;
    for (int i = tid; i < KU * D; i += BLK) {
        int k = i / D, cc = i - k * D;
        ((float*)&wp[k >> 2][cc])[k & 3] = uw[i];
    }
    __syncthreads();

    const int wave = tid >> 6, lane = tid & 63;
    const int c0 = lane, c1 = lane + 64;
    const float UBa = ub[c0], UBb = ub[c1];
    const float Ga = lg[c0], Gb = lg[c1], Ba = lb[c0], Bb = lb[c1];

    const int gw = blockIdx.x * WPB + wave;
    const int nW = gridDim.x * WPB;
    const int nPairs = (N + 1) >> 1;
    const int nIter = (nPairs + nW - 1) / nW;

    for (int it = 0; it < nIter; ++it) {
        const int p = gw + it * nW;
        const bool act = p < nPairs;
        const int r0 = act ? (p << 1) : 0;
        const int r1 = (r0 + 1 < N) ? (r0 + 1) : r0;

        float2 v;
        v = *(const float2*)&hn[(size_t)r0 * D + 2 * lane];
        yld[wave][0][2 * lane] = v.x;     yld[wave][0][2 * lane + 1] = v.y;
        v = *(const float2*)&agg[(size_t)r0 * D + 2 * lane];
        yld[wave][0][D + 2 * lane] = v.x; yld[wave][0][D + 2 * lane + 1] = v.y;
        v = *(const float2*)&hn[(size_t)r1 * D + 2 * lane];
        yld[wave][1][2 * lane] = v.x;     yld[wave][1][2 * lane + 1] = v.y;
        v = *(const float2*)&agg[(size_t)r1 * D + 2 * lane];
        yld[wave][1][D + 2 * lane] = v.x; yld[wave][1][D + 2 * lane + 1] = v.y;
        __syncthreads();

        float a00 = 0.f, a01 = 0.f, a10 = 0.f, a11 = 0.f;
        #pragma unroll 8
        for (int k4 = 0; k4 < KU / 4; ++k4) {
            const float4 wa = wp[k4][c0];
            const float4 wb = wp[k4][c1];
            const float4 f0 = *(const float4*)&yld[wave][0][4 * k4];
            const float4 f1 = *(const float4*)&yld[wave][1][4 * k4];
            a00 += f0.x * wa.x; a00 += f0.y * wa.y; a00 += f0.z * wa.z; a00 += f0.w * wa.w;
            a01 += f0.x * wb.x; a01 += f0.y * wb.y; a01 += f0.z * wb.z; a01 += f0.w * wb.w;
            a10 += f1.x * wa.x; a10 += f1.y * wa.y; a10 += f1.z * wa.z; a10 += f1.w * wa.w;
            a11 += f1.x * wb.x; a11 += f1.y * wb.y; a11 += f1.z * wb.z; a11 += f1.w * wb.w;
        }
        float v00 = a00 + UBa + x[(size_t)r0 * D + c0];
        float v01 = a01 + UBb + x[(size_t)r0 * D + c1];
        float v10 = a10 + UBa + x[(size_t)r1 * D + c0];
        float v11 = a11 + UBb + x[(size_t)r1 * D + c1];
        float m0 = v00 + v01; float q0 = v00 * v00 + v01 * v01;
        float m1 = v10 + v11; float q1 = v10 * v10 + v11 * v11;
        m0 += __shfl_xor(m0, 32, 64); q0 += __shfl_xor(q0, 32, 64);
        m0 += __shfl_xor(m0, 16, 64); q0 += __shfl_xor(q0, 16, 64);
        m0 += __shfl_xor(m0, 8, 64);  q0 += __shfl_xor(q0, 8, 64);
        m0 += __shfl_xor(m0, 4, 64);  q0 += __shfl_xor(q0, 4, 64);
        m0 += __shfl_xor(m0, 2, 64);  q0 += __shfl_xor(q0, 2, 64);
        m0 += __shfl_xor(m0, 1, 64);  q0 += __shfl_xor(q0, 1, 64);
        m1 += __shfl_xor(m1, 32, 64); q1 += __shfl_xor(q1, 32, 64);
        m1 += __shfl_xor(m1, 16, 64); q1 += __shfl_xor(q1, 16, 64);
        m1 += __shfl_xor(m1, 8, 64);  q1 += __shfl_xor(q1, 8, 64);
        m1 += __shfl_xor(m1, 4, 64);  q1 += __shfl_xor(q1, 4, 64);
        m1 += __shfl_xor(m1, 2, 64);  q1 += __shfl_xor(q1, 2, 64);
        m1 += __shfl_xor(m1, 1, 64);  q1 += __shfl_xor(q1, 1, 64);
        m0 *= (1.f / 128.f); q0 *= (1.f / 128.f);
        m1 *= (1.f / 128.f); q1 *= (1.f / 128.f);
        float rs0 = rsqrtf(q0 - m0 * m0 + 1e-5f);
        float rs1 = rsqrtf(q1 - m1 * m1 + 1e-5f);
        if (act) {
            out[(size_t)r0 * D + c0] = (v00 - m0) * rs0 * Ga + Ba;
            out[(size_t)r0 * D + c1] = (v01 - m0) * rs0 * Gb + Bb;
            out[(size_t)r1 * D + c0] = (v10 - m1) * rs1 * Ga + Ba;
            out[(size_t)r1 * D + c1] = (v11 - m1) * rs1 * Gb + Bb;
        }
    }
}

extern "C" void kernel_launch(void* const* d_in, const int* in_sizes, int n_in,
                              void* d_out, int out_size, void* d_ws, size_t ws_size,
                              hipStream_t stream)
{
    const float* x    = (const float*)d_in[0];
    const float* ea   = (const float*)d_in[1];
    const float* nw1  = (const float*)d_in[3];
    const float* nb1  = (const float*)d_in[4];
    const float* ng1  = (const float*)d_in[5];
    const float* nbe1 = (const float*)d_in[6];
    const float* nw2  = (const float*)d_in[7];
    const float* nb2  = (const float*)d_in[8];
    const float* ew1  = (const float*)d_in[9];
    const float* eb1  = (const float*)d_in[10];
    const float* eg1  = (const float*)d_in[11];
    const float* ebe1 = (const float*)d_in[12];
    const float* ew2  = (const float*)d_in[13];
    const float* eb2  = (const float*)d_in[14];
    const float* uw   = (const float*)d_in[15];
    const float* ub   = (const float*)d_in[16];
    const float* lg   = (const float*)d_in[17];
    const float* lb   = (const float*)d_in[18];
    const int*   eidx = (const int*)d_in[19];

    const int N = in_sizes[0] / D;
    const int E = in_sizes[1] / ED;

    float* h_nodes = (float*)d_ws;
    float* h_agg   = h_nodes + (size_t)N * D;
    unsigned short* xbf = (unsigned short*)(h_agg + (size_t)N * D);

    const size_t need = (size_t)N * D * 8 + (size_t)N * D * 2;
    const bool fast = ws_size >= need;

    hipMemsetAsync(h_agg, 0, (size_t)N * D * sizeof(float), stream);

    if (fast) {
        const int n8 = N * D / 8;
        cvt_x_kernel<<<(n8 + 255) / 256, 256, 0, stream>>>(x, xbf, n8);
        mlp_kernel<false, true><<<GRID, BLK, 0, stream>>>(
            x, xbf, nullptr, nullptr, nw1, nb1, ng1, nbe1, nw2, nb2, h_nodes, N, E);
        mlp_kernel<true, true><<<GRID, BLK, 0, stream>>>(
            x, xbf, ea, eidx, ew1, eb1, eg1, ebe1, ew2, eb2, h_agg, N, E);
    } else {
        mlp_kernel<false, false><<<GRID, BLK, 0, stream>>>(
            x, nullptr, nullptr, nullptr, nw1, nb1, ng1, nbe1, nw2, nb2, h_nodes, N, E);
        mlp_kernel<true, false><<<GRID, BLK, 0, stream>>>(
            x, nullptr, ea, eidx, ew1, eb1, eg1, ebe1, ew2, eb2, h_agg, N, E);
    }
    update_kernel<<<GRID, BLK, 0, stream>>>(x, h_nodes, h_agg, uw, ub, lg, lb,
                                            (float*)d_out, N);
}

// Round 5
// 553.128 us; speedup vs baseline: 2.8905x; 1.1762x over previous
//
#include <hip/hip_runtime.h>
#include <stdint.h>

#define D    128
#define ED   5
#define BLK  512
#define WPB  8
#define W1S  296   // u16 stride, 2-way-max bank pattern
#define W2S  136
#define HS   136
#define US   264
#define GRID 256

typedef __attribute__((ext_vector_type(8))) short bf16x8;
typedef __attribute__((ext_vector_type(4))) float f32x4;

__device__ __forceinline__ unsigned short f2bf(float f) {
    union { float f; uint32_t u; } c; c.f = f;
    uint32_t r = (c.u + 0x7fffu + ((c.u >> 16) & 1u)) >> 16;
    return (unsigned short)r;
}
__device__ __forceinline__ float bflo(uint32_t u) {
    union { uint32_t u; float f; } c; c.u = u << 16; return c.f;
}
__device__ __forceinline__ float bfhi(uint32_t u) {
    union { uint32_t u; float f; } c; c.u = u & 0xffff0000u; return c.f;
}
__device__ __forceinline__ bf16x8 cvt8(const float* __restrict__ p) {
    float4 a = *(const float4*)p;
    float4 b = *(const float4*)(p + 4);
    bf16x8 r;
    r[0] = (short)f2bf(a.x); r[1] = (short)f2bf(a.y);
    r[2] = (short)f2bf(a.z); r[3] = (short)f2bf(a.w);
    r[4] = (short)f2bf(b.x); r[5] = (short)f2bf(b.y);
    r[6] = (short)f2bf(b.z); r[7] = (short)f2bf(b.w);
    return r;
}
__device__ __forceinline__ bool detect64(const int* ei) {
    return (ei[1] == 0) & (ei[3] == 0) & (ei[5] == 0) &
           (ei[7] == 0) & (ei[9] == 0) & (ei[11] == 0);
}

__global__ __launch_bounds__(256)
void cvt_x_kernel(const float* __restrict__ in, unsigned short* __restrict__ out, int n8) {
    int i = blockIdx.x * blockDim.x + threadIdx.x;
    if (i >= n8) return;
    float4 a = ((const float4*)in)[2 * i];
    float4 b = ((const float4*)in)[2 * i + 1];
    union { unsigned short s[8]; uint4 v; } p;
    p.s[0] = f2bf(a.x); p.s[1] = f2bf(a.y); p.s[2] = f2bf(a.z); p.s[3] = f2bf(a.w);
    p.s[4] = f2bf(b.x); p.s[5] = f2bf(b.y); p.s[6] = f2bf(b.z); p.s[7] = f2bf(b.w);
    ((uint4*)out)[i] = p.v;
}

// ---------------- CSR build ----------------
__global__ __launch_bounds__(512)
void count_kernel(const int* __restrict__ ei, int* __restrict__ cnt, int E) {
    const bool is64 = detect64(ei);
    int e = blockIdx.x * 512 + threadIdx.x;
    if (e >= E) return;
    int d = is64 ? ei[2 * ((size_t)E + e)] : ei[(size_t)E + e];
    atomicAdd(&cnt[d], 1);
}

__global__ __launch_bounds__(1024)
void scan_kernel(const int* __restrict__ cnt, int* __restrict__ starts,
                 int* __restrict__ cursor, int N) {
    __shared__ int wsum[16];
    __shared__ int carrySh;
    const int tid = threadIdx.x, wave = tid >> 6, lane = tid & 63;
    if (tid == 0) carrySh = 0;
    __syncthreads();
    for (int base = 0; base < N; base += 1024) {
        const int idx = base + tid;
        int v = (idx < N) ? cnt[idx] : 0;
        int s = v;
        #pragma unroll
        for (int off = 1; off < 64; off <<= 1) {
            int t = __shfl_up(s, off, 64);
            if (lane >= off) s += t;
        }
        if (lane == 63) wsum[wave] = s;
        __syncthreads();
        if (wave == 0 && lane < 16) {
            int ws_ = wsum[lane];
            #pragma unroll
            for (int off = 1; off < 16; off <<= 1) {
                int t = __shfl_up(ws_, off, 64);
                if (lane >= off) ws_ += t;
            }
            wsum[lane] = ws_;
        }
        __syncthreads();
        const int wpre = (wave == 0) ? 0 : wsum[wave - 1];
        const int carry = carrySh;
        const int excl = carry + wpre + (s - v);
        if (idx < N) { starts[idx] = excl; cursor[idx] = excl; }
        __syncthreads();
        if (tid == 1023) carrySh = carry + wsum[15];
        __syncthreads();
    }
    if (threadIdx.x == 0) starts[N] = carrySh;
}

__global__ __launch_bounds__(512)
void fill_kernel(const int* __restrict__ ei, int* __restrict__ cursor,
                 int* __restrict__ eids, int E) {
    const bool is64 = detect64(ei);
    int e = blockIdx.x * 512 + threadIdx.x;
    if (e >= E) return;
    int d = is64 ? ei[2 * ((size_t)E + e)] : ei[(size_t)E + e];
    int pos = atomicAdd(&cursor[d], 1);
    eids[pos] = e;
}

// ---- per-dst gather-sum: agg_bf[n] = sum_{e in CSR[n]} h2[e] ----
__global__ __launch_bounds__(512)
void agg_kernel(const unsigned short* __restrict__ h2, const int* __restrict__ starts,
                const int* __restrict__ eids, unsigned short* __restrict__ aggb, int N) {
    const int wid = blockIdx.x * WPB + (threadIdx.x >> 6);
    if (wid >= N) return;
    const int lane = threadIdx.x & 63;
    const int s = starts[wid], t = starts[wid + 1];
    float a0 = 0.f, a1 = 0.f;
    for (int j = s; j < t; ++j) {
        const int e = eids[j];
        uint32_t u = *(const uint32_t*)(h2 + (size_t)e * D + 2 * lane);
        a0 += bflo(u); a1 += bfhi(u);
    }
    uint32_t o = (uint32_t)f2bf(a0) | ((uint32_t)f2bf(a1) << 16);
    *(uint32_t*)(aggb + (size_t)wid * D + 2 * lane) = o;
}

// One wave = one 16-row m-tile. GEMM1 -> LN+ReLU -> LDS transpose -> GEMM2.
// Epilogue: node -> hn_bf rows; edge CSR -> h2 rows; edge !CSR -> atomics.
template<bool EDGE, bool XBF, bool CSR>
__global__ __launch_bounds__(BLK, 1)
void mlp_kernel(const float* __restrict__ x, const unsigned short* __restrict__ xbf,
                const float* __restrict__ ea, const int* __restrict__ ei,
                const float* __restrict__ w1, const float* __restrict__ b1,
                const float* __restrict__ g1, const float* __restrict__ be1,
                const float* __restrict__ w2, const float* __restrict__ b2,
                unsigned short* __restrict__ hout, float* __restrict__ aggf,
                int N, int E)
{
    __shared__ unsigned short w1t[128 * W1S];
    __shared__ unsigned short w2t[128 * W2S];
    __shared__ unsigned short hb[WPB][16 * HS];

    const int tid = threadIdx.x;
    const int KROWS = EDGE ? 288 : 128;
    for (int i = tid; i < KROWS * 128; i += BLK) {
        int k = i >> 7, n = i & 127;
        float v = (!EDGE || k < (2 * D + ED)) ? w1[k * 128 + n] : 0.f;
        w1t[n * W1S + k] = f2bf(v);
    }
    for (int i = tid; i < 128 * 128; i += BLK) {
        int k = i >> 7, n = i & 127;
        w2t[n * W2S + k] = f2bf(w2[k * 128 + n]);
    }
    __syncthreads();

    bool is64 = false;
    if (EDGE) is64 = detect64(ei);

    const int lane = tid & 63, w = tid >> 6;
    const int g = lane >> 4, c = lane & 15;

    float b1v[8], g1v[8], e1v[8], b2v[8];
    #pragma unroll
    for (int nt = 0; nt < 8; ++nt) {
        b1v[nt] = b1[nt * 16 + c];  g1v[nt] = g1[nt * 16 + c];
        e1v[nt] = be1[nt * 16 + c]; b2v[nt] = b2[nt * 16 + c];
    }

    const int cnt = EDGE ? E : N;
    const int nT = (cnt + 15) >> 4;
    unsigned short* hw = hb[w];

    for (int tile = blockIdx.x * WPB + w; tile < nT; tile += gridDim.x * WPB) {
        const int row = tile * 16 + c;
        const int rc  = row < cnt ? row : cnt - 1;

        int dd = 0;
        size_t aoff = 0, boff = 0;
        if (EDGE) {
            int s = is64 ? ei[2 * (size_t)rc]       : ei[rc];
            dd    = is64 ? ei[2 * ((size_t)E + rc)] : ei[(size_t)E + rc];
            aoff = (size_t)s * D;
            boff = (size_t)dd * D;
        } else {
            aoff = (size_t)rc * D;
        }

        const f32x4 z = {0.f, 0.f, 0.f, 0.f};
        f32x4 acc[8] = {z, z, z, z, z, z, z, z};

        #pragma unroll
        for (int kk = 0; kk < (EDGE ? 9 : 4); ++kk) {
            bf16x8 af;
            if (!EDGE || kk < 4) {
                if (XBF) af = *(const bf16x8*)(xbf + aoff + kk * 32 + 8 * g);
                else     af = cvt8(x + aoff + kk * 32 + 8 * g);
            } else if (kk < 8) {
                if (XBF) af = *(const bf16x8*)(xbf + boff + (kk - 4) * 32 + 8 * g);
                else     af = cvt8(x + boff + (kk - 4) * 32 + 8 * g);
            } else {
                #pragma unroll
                for (int j = 0; j < 8; ++j) af[j] = 0;
                if (g == 0) {
                    #pragma unroll
                    for (int j = 0; j < ED; ++j)
                        af[j] = (short)f2bf(ea[(size_t)rc * ED + j]);
                }
            }
            const unsigned short* wr = &w1t[c * W1S + kk * 32 + 8 * g];
            #pragma unroll
            for (int nt = 0; nt < 8; ++nt) {
                bf16x8 bf = *(const bf16x8*)(wr + nt * 16 * W1S);
                acc[nt] = __builtin_amdgcn_mfma_f32_16x16x32_bf16(af, bf, acc[nt], 0, 0, 0);
            }
        }

        // bias + LN + ReLU; C layout: col = nt*16+c, row = 4g+r
        float mean[4], rstd[4];
        #pragma unroll
        for (int r = 0; r < 4; ++r) {
            float s = 0.f, q = 0.f;
            #pragma unroll
            for (int nt = 0; nt < 8; ++nt) {
                float v = acc[nt][r] + b1v[nt];
                acc[nt][r] = v;
                s += v; q += v * v;
            }
            s += __shfl_xor(s, 1, 64); q += __shfl_xor(q, 1, 64);
            s += __shfl_xor(s, 2, 64); q += __shfl_xor(q, 2, 64);
            s += __shfl_xor(s, 4, 64); q += __shfl_xor(q, 4, 64);
            s += __shfl_xor(s, 8, 64); q += __shfl_xor(q, 8, 64);
            float m = s * (1.f / 128.f);
            float var = q * (1.f / 128.f) - m * m;
            mean[r] = m;
            rstd[r] = rsqrtf(var + 1e-5f);
        }
        #pragma unroll
        for (int nt = 0; nt < 8; ++nt) {
            #pragma unroll
            for (int r = 0; r < 4; ++r) {
                float h = fmaxf((acc[nt][r] - mean[r]) * rstd[r] * g1v[nt] + e1v[nt], 0.f);
                hw[(4 * g + r) * HS + nt * 16 + c] = f2bf(h);
            }
        }
        // wave-private tile: same-wave DS ordering suffices

        f32x4 acc2[8] = {z, z, z, z, z, z, z, z};
        #pragma unroll
        for (int kk = 0; kk < 4; ++kk) {
            bf16x8 af = *(const bf16x8*)&hw[c * HS + kk * 32 + 8 * g];
            const unsigned short* wr = &w2t[c * W2S + kk * 32 + 8 * g];
            #pragma unroll
            for (int nt = 0; nt < 8; ++nt) {
                bf16x8 bf = *(const bf16x8*)(wr + nt * 16 * W2S);
                acc2[nt] = __builtin_amdgcn_mfma_f32_16x16x32_bf16(af, bf, acc2[nt], 0, 0, 0);
            }
        }

        if (EDGE && !CSR) {
            int dv[4];
            #pragma unroll
            for (int r = 0; r < 4; ++r) dv[r] = __shfl(dd, 4 * g + r, 64);
            #pragma unroll
            for (int r = 0; r < 4; ++r) {
                const int er = tile * 16 + 4 * g + r;
                if (er < cnt) {
                    float* dst = aggf + (size_t)dv[r] * D + c;
                    #pragma unroll
                    for (int nt = 0; nt < 8; ++nt)
                        atomicAdd(dst + nt * 16, acc2[nt][r] + b2v[nt]);
                }
            }
        } else {
            // bf16 row write (hn_bf for node, h2 for edge) via LDS transpose
            #pragma unroll
            for (int nt = 0; nt < 8; ++nt) {
                #pragma unroll
                for (int r = 0; r < 4; ++r)
                    hw[(4 * g + r) * HS + nt * 16 + c] = f2bf(acc2[nt][r] + b2v[nt]);
            }
            if (row < cnt) {
                unsigned short* dst = hout + (size_t)row * D;
                #pragma unroll
                for (int j = 0; j < 4; ++j)
                    *(uint4*)(dst + (j * 4 + g) * 8) =
                        *(const uint4*)&hw[c * HS + (j * 4 + g) * 8];
            }
        }
    }
}

// ---- update (MFMA): out = LN(concat(hn,agg)@uw + ub + x) ----
template<bool AGGBF, bool XBF>
__global__ __launch_bounds__(BLK, 4)
void upd2_kernel(const unsigned short* __restrict__ hnb, const void* __restrict__ aggp,
                 const float* __restrict__ x, const unsigned short* __restrict__ xbf,
                 const float* __restrict__ uw, const float* __restrict__ ub,
                 const float* __restrict__ lg, const float* __restrict__ lb,
                 float* __restrict__ out, int N)
{
    __shared__ unsigned short wt[128 * US];
    const int tid = threadIdx.x;
    for (int i = tid; i < 256 * 128; i += BLK) {
        int k = i >> 7, n = i & 127;
        wt[n * US + k] = f2bf(uw[i]);
    }
    __syncthreads();

    const int lane = tid & 63, w = tid >> 6;
    const int g = lane >> 4, c = lane & 15;

    float ubv[8], gv[8], bv[8];
    #pragma unroll
    for (int nt = 0; nt < 8; ++nt) {
        ubv[nt] = ub[nt * 16 + c]; gv[nt] = lg[nt * 16 + c]; bv[nt] = lb[nt * 16 + c];
    }

    const int nT = (N + 15) >> 4;
    for (int tile = blockIdx.x * WPB + w; tile < nT; tile += gridDim.x * WPB) {
        const int row = tile * 16 + c;
        const int rc  = row < N ? row : N - 1;

        const f32x4 z = {0.f, 0.f, 0.f, 0.f};
        f32x4 acc[8] = {z, z, z, z, z, z, z, z};

        #pragma unroll
        for (int kk = 0; kk < 8; ++kk) {
            bf16x8 af;
            if (kk < 4) {
                af = *(const bf16x8*)(hnb + (size_t)rc * D + kk * 32 + 8 * g);
            } else {
                if (AGGBF)
                    af = *(const bf16x8*)((const unsigned short*)aggp +
                                          (size_t)rc * D + (kk - 4) * 32 + 8 * g);
                else
                    af = cvt8((const float*)aggp + (size_t)rc * D + (kk - 4) * 32 + 8 * g);
            }
            const unsigned short* wr = &wt[c * US + kk * 32 + 8 * g];
            #pragma unroll
            for (int nt = 0; nt < 8; ++nt) {
                bf16x8 bf = *(const bf16x8*)(wr + nt * 16 * US);
                acc[nt] = __builtin_amdgcn_mfma_f32_16x16x32_bf16(af, bf, acc[nt], 0, 0, 0);
            }
        }

        float mean[4], rstd[4];
        #pragma unroll
        for (int r = 0; r < 4; ++r) {
            const int row4 = tile * 16 + 4 * g + r;
            const int r4c = row4 < N ? row4 : N - 1;
            float s = 0.f, q = 0.f;
            #pragma unroll
            for (int nt = 0; nt < 8; ++nt) {
                float xr;
                if (XBF) xr = bflo((uint32_t)xbf[(size_t)r4c * D + nt * 16 + c]);
                else     xr = x[(size_t)r4c * D + nt * 16 + c];
                float v = acc[nt][r] + ubv[nt] + xr;
                acc[nt][r] = v;
                s += v; q += v * v;
            }
            s += __shfl_xor(s, 1, 64); q += __shfl_xor(q, 1, 64);
            s += __shfl_xor(s, 2, 64); q += __shfl_xor(q, 2, 64);
            s += __shfl_xor(s, 4, 64); q += __shfl_xor(q, 4, 64);
            s += __shfl_xor(s, 8, 64); q += __shfl_xor(q, 8, 64);
            float m = s * (1.f / 128.f);
            mean[r] = m;
            rstd[r] = rsqrtf(q * (1.f / 128.f) - m * m + 1e-5f);
        }
        #pragma unroll
        for (int r = 0; r < 4; ++r) {
            const int row4 = tile * 16 + 4 * g + r;
            if (row4 < N) {
                #pragma unroll
                for (int nt = 0; nt < 8; ++nt)
                    out[(size_t)row4 * D + nt * 16 + c] =
                        (acc[nt][r] - mean[r]) * rstd[r] * gv[nt] + bv[nt];
            }
        }
    }
}

extern "C" void kernel_launch(void* const* d_in, const int* in_sizes, int n_in,
                              void* d_out, int out_size, void* d_ws, size_t ws_size,
                              hipStream_t stream)
{
    const float* x    = (const float*)d_in[0];
    const float* ea   = (const float*)d_in[1];
    const float* nw1  = (const float*)d_in[3];
    const float* nb1  = (const float*)d_in[4];
    const float* ng1  = (const float*)d_in[5];
    const float* nbe1 = (const float*)d_in[6];
    const float* nw2  = (const float*)d_in[7];
    const float* nb2  = (const float*)d_in[8];
    const float* ew1  = (const float*)d_in[9];
    const float* eb1  = (const float*)d_in[10];
    const float* eg1  = (const float*)d_in[11];
    const float* ebe1 = (const float*)d_in[12];
    const float* ew2  = (const float*)d_in[13];
    const float* eb2  = (const float*)d_in[14];
    const float* uw   = (const float*)d_in[15];
    const float* ub   = (const float*)d_in[16];
    const float* lg   = (const float*)d_in[17];
    const float* lb   = (const float*)d_in[18];
    const int*   eidx = (const int*)d_in[19];

    const int N = in_sizes[0] / D;
    const int E = in_sizes[1] / ED;

    char* base = (char*)d_ws;
    size_t off = 0;
    auto alloc = [&](size_t bytes) -> char* {
        char* p = base + off;
        off = (off + bytes + 255) & ~(size_t)255;
        return p;
    };

    // Tier A layout (CSR)
    unsigned short* hnb  = (unsigned short*)alloc((size_t)N * D * 2);
    unsigned short* aggb = (unsigned short*)alloc((size_t)N * D * 2);
    unsigned short* xbf  = (unsigned short*)alloc((size_t)N * D * 2);
    int* cnt    = (int*)alloc((size_t)N * 4);
    int* starts = (int*)alloc(((size_t)N + 1) * 4);
    int* cursor = (int*)alloc((size_t)N * 4);
    int* eids   = (int*)alloc((size_t)E * 4);
    unsigned short* h2 = (unsigned short*)alloc((size_t)E * D * 2);
    const size_t needA = off;

    const int n8 = N * D / 8;
    const int egrid = (E + 511) / 512;
    const int ugrid = (((N + 15) / 16) + WPB - 1) / WPB;

    if (ws_size >= needA) {
        hipMemsetAsync(cnt, 0, (size_t)N * 4, stream);
        cvt_x_kernel<<<(n8 + 255) / 256, 256, 0, stream>>>(x, xbf, n8);
        count_kernel<<<egrid, 512, 0, stream>>>(eidx, cnt, E);
        scan_kernel<<<1, 1024, 0, stream>>>(cnt, starts, cursor, N);
        fill_kernel<<<egrid, 512, 0, stream>>>(eidx, cursor, eids, E);
        mlp_kernel<false, true, true><<<GRID, BLK, 0, stream>>>(
            x, xbf, nullptr, nullptr, nw1, nb1, ng1, nbe1, nw2, nb2, hnb, nullptr, N, E);
        mlp_kernel<true, true, true><<<GRID, BLK, 0, stream>>>(
            x, xbf, ea, eidx, ew1, eb1, eg1, ebe1, ew2, eb2, h2, nullptr, N, E);
        agg_kernel<<<(N + WPB - 1) / WPB, 512, 0, stream>>>(h2, starts, eids, aggb, N);
        upd2_kernel<true, true><<<ugrid, BLK, 0, stream>>>(
            hnb, aggb, x, xbf, uw, ub, lg, lb, (float*)d_out, N);
        return;
    }

    // Tier B layout (atomics, f32 agg) — 51.2 MB, proven available
    off = 0;
    unsigned short* hnb2 = (unsigned short*)alloc((size_t)N * D * 2);
    float* aggf = (float*)alloc((size_t)N * D * 4);
    unsigned short* xbf2 = (unsigned short*)alloc((size_t)N * D * 2);
    const size_t needB = off;

    hipMemsetAsync(aggf, 0, (size_t)N * D * 4, stream);
    if (ws_size >= needB) {
        cvt_x_kernel<<<(n8 + 255) / 256, 256, 0, stream>>>(x, xbf2, n8);
        mlp_kernel<false, true, false><<<GRID, BLK, 0, stream>>>(
            x, xbf2, nullptr, nullptr, nw1, nb1, ng1, nbe1, nw2, nb2, hnb2, nullptr, N, E);
        mlp_kernel<true, true, false><<<GRID, BLK, 0, stream>>>(
            x, xbf2, ea, eidx, ew1, eb1, eg1, ebe1, ew2, eb2, nullptr, aggf, N, E);
        upd2_kernel<false, true><<<ugrid, BLK, 0, stream>>>(
            hnb2, aggf, x, xbf2, uw, ub, lg, lb, (float*)d_out, N);
    } else {
        // Tier C: no xbf (38.4 MB)
        mlp_kernel<false, false, false><<<GRID, BLK, 0, stream>>>(
            x, nullptr, nullptr, nullptr, nw1, nb1, ng1, nbe1, nw2, nb2, hnb2, nullptr, N, E);
        mlp_kernel<true, false, false><<<GRID, BLK, 0, stream>>>(
            x, nullptr, ea, eidx, ew1, eb1, eg1, ebe1, ew2, eb2, nullptr, aggf, N, E);
        upd2_kernel<false, false><<<ugrid, BLK, 0, stream>>>(
            hnb2, aggf, x, nullptr, uw, ub, lg, lb, (float*)d_out, N);
    }
}

// Round 6
// 477.492 us; speedup vs baseline: 3.3484x; 1.1584x over previous
//
#include <hip/hip_runtime.h>
#include <stdint.h>

#define D    128
#define ED   5
#define BLK  512
#define WPB  8
#define W1S  296   // u16 stride, 16B-aligned rows
#define W2S  136
#define HS   136
#define US   264
#define GRID 256

typedef __attribute__((ext_vector_type(8))) short bf16x8;
typedef __attribute__((ext_vector_type(4))) float f32x4;

__device__ __forceinline__ unsigned short f2bf(float f) {
    union { float f; uint32_t u; } c; c.f = f;
    uint32_t r = (c.u + 0x7fffu + ((c.u >> 16) & 1u)) >> 16;
    return (unsigned short)r;
}
__device__ __forceinline__ float bflo(uint32_t u) {
    union { uint32_t u; float f; } c; c.u = u << 16; return c.f;
}
__device__ __forceinline__ float bfhi(uint32_t u) {
    union { uint32_t u; float f; } c; c.u = u & 0xffff0000u; return c.f;
}
__device__ __forceinline__ bf16x8 cvt8(const float* __restrict__ p) {
    float4 a = *(const float4*)p;
    float4 b = *(const float4*)(p + 4);
    bf16x8 r;
    r[0] = (short)f2bf(a.x); r[1] = (short)f2bf(a.y);
    r[2] = (short)f2bf(a.z); r[3] = (short)f2bf(a.w);
    r[4] = (short)f2bf(b.x); r[5] = (short)f2bf(b.y);
    r[6] = (short)f2bf(b.z); r[7] = (short)f2bf(b.w);
    return r;
}
__device__ __forceinline__ bool detect64(const int* ei) {
    return (ei[1] == 0) & (ei[3] == 0) & (ei[5] == 0) &
           (ei[7] == 0) & (ei[9] == 0) & (ei[11] == 0);
}

__global__ __launch_bounds__(256)
void cvt_x_kernel(const float* __restrict__ in, unsigned short* __restrict__ out, int n8) {
    int i = blockIdx.x * blockDim.x + threadIdx.x;
    if (i >= n8) return;
    float4 a = ((const float4*)in)[2 * i];
    float4 b = ((const float4*)in)[2 * i + 1];
    union { unsigned short s[8]; uint4 v; } p;
    p.s[0] = f2bf(a.x); p.s[1] = f2bf(a.y); p.s[2] = f2bf(a.z); p.s[3] = f2bf(a.w);
    p.s[4] = f2bf(b.x); p.s[5] = f2bf(b.y); p.s[6] = f2bf(b.z); p.s[7] = f2bf(b.w);
    ((uint4*)out)[i] = p.v;
}

// ---------------- CSR build (parallel scan) ----------------
__global__ __launch_bounds__(512)
void count_kernel(const int* __restrict__ ei, int* __restrict__ cnt, int E) {
    const bool is64 = detect64(ei);
    int e = blockIdx.x * 512 + threadIdx.x;
    if (e >= E) return;
    int d = is64 ? ei[2 * ((size_t)E + e)] : ei[(size_t)E + e];
    atomicAdd(&cnt[d], 1);
}

__global__ __launch_bounds__(1024)
void scan_blk_kernel(const int* __restrict__ cnt, int* __restrict__ part,
                     int* __restrict__ bsum, int N) {
    __shared__ int wsum[16];
    const int tid = threadIdx.x, wave = tid >> 6, lane = tid & 63;
    const int idx = blockIdx.x * 1024 + tid;
    int v = (idx < N) ? cnt[idx] : 0;
    int s = v;
    #pragma unroll
    for (int off = 1; off < 64; off <<= 1) {
        int t = __shfl_up(s, off, 64);
        if (lane >= off) s += t;
    }
    if (lane == 63) wsum[wave] = s;
    __syncthreads();
    if (wave == 0 && lane < 16) {
        int ws_ = wsum[lane];
        #pragma unroll
        for (int off = 1; off < 16; off <<= 1) {
            int t = __shfl_up(ws_, off, 64);
            if (lane >= off) ws_ += t;
        }
        wsum[lane] = ws_;
    }
    __syncthreads();
    const int excl = ((wave == 0) ? 0 : wsum[wave - 1]) + (s - v);
    if (idx < N) part[idx] = excl;
    if (tid == 0) bsum[blockIdx.x] = wsum[15];
}

__global__ __launch_bounds__(1024)
void scan_top_kernel(int* __restrict__ bsum, int nb) {
    __shared__ int wsum[16];
    const int tid = threadIdx.x, wave = tid >> 6, lane = tid & 63;
    int v = (tid < nb) ? bsum[tid] : 0;
    int s = v;
    #pragma unroll
    for (int off = 1; off < 64; off <<= 1) {
        int t = __shfl_up(s, off, 64);
        if (lane >= off) s += t;
    }
    if (lane == 63) wsum[wave] = s;
    __syncthreads();
    if (wave == 0 && lane < 16) {
        int ws_ = wsum[lane];
        #pragma unroll
        for (int off = 1; off < 16; off <<= 1) {
            int t = __shfl_up(ws_, off, 64);
            if (lane >= off) ws_ += t;
        }
        wsum[lane] = ws_;
    }
    __syncthreads();
    const int excl = ((wave == 0) ? 0 : wsum[wave - 1]) + (s - v);
    if (tid < nb) bsum[tid] = excl;
}

__global__ __launch_bounds__(1024)
void scan_add_kernel(const int* __restrict__ part, const int* __restrict__ bsum,
                     int* __restrict__ starts, int* __restrict__ cursor,
                     int N, int E) {
    const int idx = blockIdx.x * 1024 + threadIdx.x;
    if (idx < N) {
        int v = part[idx] + bsum[blockIdx.x];
        starts[idx] = v;
        cursor[idx] = v;
    }
    if (blockIdx.x == 0 && threadIdx.x == 0) starts[N] = E;
}

__global__ __launch_bounds__(512)
void fill_kernel(const int* __restrict__ ei, int* __restrict__ cursor,
                 int* __restrict__ eids, int E) {
    const bool is64 = detect64(ei);
    int e = blockIdx.x * 512 + threadIdx.x;
    if (e >= E) return;
    int d = is64 ? ei[2 * ((size_t)E + e)] : ei[(size_t)E + e];
    int pos = atomicAdd(&cursor[d], 1);
    eids[pos] = e;
}

// ---- per-dst gather-sum, 4-deep ILP: agg_bf[n] = sum_{e in CSR[n]} h2[e] ----
__global__ __launch_bounds__(512)
void agg_kernel(const unsigned short* __restrict__ h2, const int* __restrict__ starts,
                const int* __restrict__ eids, unsigned short* __restrict__ aggb, int N) {
    const int wid = blockIdx.x * WPB + (threadIdx.x >> 6);
    if (wid >= N) return;
    const int lane = threadIdx.x & 63;
    const int s = starts[wid], t = starts[wid + 1];
    float a0 = 0.f, a1 = 0.f, b0 = 0.f, b1 = 0.f;
    float p0 = 0.f, p1 = 0.f, q0 = 0.f, q1 = 0.f;
    int j = s;
    for (; j + 4 <= t; j += 4) {
        const int e0 = eids[j], e1 = eids[j + 1], e2 = eids[j + 2], e3 = eids[j + 3];
        uint32_t u0 = *(const uint32_t*)(h2 + (size_t)e0 * D + 2 * lane);
        uint32_t u1 = *(const uint32_t*)(h2 + (size_t)e1 * D + 2 * lane);
        uint32_t u2 = *(const uint32_t*)(h2 + (size_t)e2 * D + 2 * lane);
        uint32_t u3 = *(const uint32_t*)(h2 + (size_t)e3 * D + 2 * lane);
        a0 += bflo(u0); a1 += bfhi(u0);
        b0 += bflo(u1); b1 += bfhi(u1);
        p0 += bflo(u2); p1 += bfhi(u2);
        q0 += bflo(u3); q1 += bfhi(u3);
    }
    for (; j < t; ++j) {
        const int e = eids[j];
        uint32_t u = *(const uint32_t*)(h2 + (size_t)e * D + 2 * lane);
        a0 += bflo(u); a1 += bfhi(u);
    }
    const float r0 = (a0 + b0) + (p0 + q0);
    const float r1 = (a1 + b1) + (p1 + q1);
    uint32_t o = (uint32_t)f2bf(r0) | ((uint32_t)f2bf(r1) << 16);
    *(uint32_t*)(aggb + (size_t)wid * D + 2 * lane) = o;
}

// One wave = one 16-row m-tile, software-pipelined gathers.
// GEMM1 -> LN+ReLU -> LDS transpose -> GEMM2.
// Epilogue: node -> hn_bf rows; edge CSR -> h2 rows; edge !CSR -> atomics.
template<bool EDGE, bool XBF, bool CSR>
__global__ __launch_bounds__(BLK, 2)
void mlp_kernel(const float* __restrict__ x, const unsigned short* __restrict__ xbf,
                const float* __restrict__ ea, const int* __restrict__ ei,
                const float* __restrict__ w1, const float* __restrict__ b1,
                const float* __restrict__ g1, const float* __restrict__ be1,
                const float* __restrict__ w2, const float* __restrict__ b2,
                unsigned short* __restrict__ hout, float* __restrict__ aggf,
                int N, int E)
{
    __shared__ unsigned short w1t[128 * W1S];
    __shared__ unsigned short w2t[128 * W2S];
    __shared__ unsigned short hb[WPB][16 * HS];

    const int tid = threadIdx.x;
    const int KROWS = EDGE ? 288 : 128;
    for (int i = tid; i < KROWS * 128; i += BLK) {
        int k = i >> 7, n = i & 127;
        float v = (!EDGE || k < (2 * D + ED)) ? w1[k * 128 + n] : 0.f;
        w1t[n * W1S + k] = f2bf(v);
    }
    for (int i = tid; i < 128 * 128; i += BLK) {
        int k = i >> 7, n = i & 127;
        w2t[n * W2S + k] = f2bf(w2[k * 128 + n]);
    }
    __syncthreads();

    bool is64 = false;
    if (EDGE) is64 = detect64(ei);

    const int lane = tid & 63, w = tid >> 6;
    const int g = lane >> 4, c = lane & 15;

    float b1v[8], g1v[8], e1v[8], b2v[8];
    #pragma unroll
    for (int nt = 0; nt < 8; ++nt) {
        b1v[nt] = b1[nt * 16 + c];  g1v[nt] = g1[nt * 16 + c];
        e1v[nt] = be1[nt * 16 + c]; b2v[nt] = b2[nt * 16 + c];
    }

    const int cnt = EDGE ? E : N;
    const int nT = (cnt + 15) >> 4;
    const int step = gridDim.x * WPB;
    unsigned short* hw = hb[w];

    // ---- software-pipeline state: indices + A-fragments of the NEXT tile ----
    int pdd = 0, prc = 0;
    size_t paoff = 0, pboff = 0;
    bf16x8 pf[9];

    auto loadIdx = [&](int tl) {
        const int rr = tl * 16 + c;
        const int rc = rr < cnt ? rr : cnt - 1;
        prc = rc;
        if (EDGE) {
            int s = is64 ? ei[2 * (size_t)rc]       : ei[rc];
            pdd   = is64 ? ei[2 * ((size_t)E + rc)] : ei[(size_t)E + rc];
            paoff = (size_t)s * D;
            pboff = (size_t)pdd * D;
        } else {
            paoff = (size_t)rc * D;
        }
    };
    auto loadFrags = [&]() {
        #pragma unroll
        for (int kk = 0; kk < (EDGE ? 8 : 4); ++kk) {
            const size_t o = (kk < 4) ? paoff + kk * 32 : pboff + (kk - 4) * 32;
            if (XBF) pf[kk] = *(const bf16x8*)(xbf + o + 8 * g);
            else     pf[kk] = cvt8(x + o + 8 * g);
        }
        if (EDGE) {
            bf16x8 t;
            #pragma unroll
            for (int j = 0; j < 8; ++j) t[j] = 0;
            if (g == 0) {
                #pragma unroll
                for (int j = 0; j < ED; ++j)
                    t[j] = (short)f2bf(ea[(size_t)prc * ED + j]);
            }
            pf[8] = t;
        }
    };

    int tile = blockIdx.x * WPB + w;
    if (tile < nT) { loadIdx(tile); loadFrags(); }

    for (; tile < nT; tile += step) {
        // consume prefetched state
        bf16x8 af[9];
        #pragma unroll
        for (int kk = 0; kk < (EDGE ? 9 : 4); ++kk) af[kk] = pf[kk];
        const int dd = pdd;
        const int row = tile * 16 + c;

        // issue next tile's index loads (land during GEMM1)
        const int tn = tile + step;
        loadIdx(tn < nT ? tn : tile);

        const f32x4 z = {0.f, 0.f, 0.f, 0.f};
        f32x4 acc[8] = {z, z, z, z, z, z, z, z};
        #pragma unroll
        for (int kk = 0; kk < (EDGE ? 9 : 4); ++kk) {
            const unsigned short* wr = &w1t[c * W1S + kk * 32 + 8 * g];
            #pragma unroll
            for (int nt = 0; nt < 8; ++nt) {
                bf16x8 bf = *(const bf16x8*)(wr + nt * 16 * W1S);
                acc[nt] = __builtin_amdgcn_mfma_f32_16x16x32_bf16(af[kk], bf, acc[nt], 0, 0, 0);
            }
        }

        // issue next tile's gathers (hidden under LN + transpose + GEMM2)
        loadFrags();

        // bias + LN + ReLU; C layout: col = nt*16+c, row = 4g+r
        float mean[4], rstd[4];
        #pragma unroll
        for (int r = 0; r < 4; ++r) {
            float s = 0.f, q = 0.f;
            #pragma unroll
            for (int nt = 0; nt < 8; ++nt) {
                float v = acc[nt][r] + b1v[nt];
                acc[nt][r] = v;
                s += v; q += v * v;
            }
            s += __shfl_xor(s, 1, 64); q += __shfl_xor(q, 1, 64);
            s += __shfl_xor(s, 2, 64); q += __shfl_xor(q, 2, 64);
            s += __shfl_xor(s, 4, 64); q += __shfl_xor(q, 4, 64);
            s += __shfl_xor(s, 8, 64); q += __shfl_xor(q, 8, 64);
            float m = s * (1.f / 128.f);
            float var = q * (1.f / 128.f) - m * m;
            mean[r] = m;
            rstd[r] = rsqrtf(var + 1e-5f);
        }
        #pragma unroll
        for (int nt = 0; nt < 8; ++nt) {
            #pragma unroll
            for (int r = 0; r < 4; ++r) {
                float h = fmaxf((acc[nt][r] - mean[r]) * rstd[r] * g1v[nt] + e1v[nt], 0.f);
                hw[(4 * g + r) * HS + nt * 16 + c] = f2bf(h);
            }
        }
        // wave-private tile: same-wave DS ordering suffices

        f32x4 acc2[8] = {z, z, z, z, z, z, z, z};
        #pragma unroll
        for (int kk = 0; kk < 4; ++kk) {
            bf16x8 hf = *(const bf16x8*)&hw[c * HS + kk * 32 + 8 * g];
            const unsigned short* wr = &w2t[c * W2S + kk * 32 + 8 * g];
            #pragma unroll
            for (int nt = 0; nt < 8; ++nt) {
                bf16x8 bf = *(const bf16x8*)(wr + nt * 16 * W2S);
                acc2[nt] = __builtin_amdgcn_mfma_f32_16x16x32_bf16(hf, bf, acc2[nt], 0, 0, 0);
            }
        }

        if (EDGE && !CSR) {
            int dv[4];
            #pragma unroll
            for (int r = 0; r < 4; ++r) dv[r] = __shfl(dd, 4 * g + r, 64);
            #pragma unroll
            for (int r = 0; r < 4; ++r) {
                const int er = tile * 16 + 4 * g + r;
                if (er < cnt) {
                    float* dst = aggf + (size_t)dv[r] * D + c;
                    #pragma unroll
                    for (int nt = 0; nt < 8; ++nt)
                        atomicAdd(dst + nt * 16, acc2[nt][r] + b2v[nt]);
                }
            }
        } else {
            // bf16 row write (hn_bf for node, h2 for edge) via LDS transpose
            #pragma unroll
            for (int nt = 0; nt < 8; ++nt) {
                #pragma unroll
                for (int r = 0; r < 4; ++r)
                    hw[(4 * g + r) * HS + nt * 16 + c] = f2bf(acc2[nt][r] + b2v[nt]);
            }
            if (row < cnt) {
                unsigned short* dst = hout + (size_t)row * D;
                #pragma unroll
                for (int j = 0; j < 4; ++j)
                    *(uint4*)(dst + (j * 4 + g) * 8) =
                        *(const uint4*)&hw[c * HS + (j * 4 + g) * 8];
            }
        }
    }
}

// ---- update (MFMA): out = LN(concat(hn,agg)@uw + ub + x) ----
template<bool AGGBF, bool XBF>
__global__ __launch_bounds__(BLK, 4)
void upd2_kernel(const unsigned short* __restrict__ hnb, const void* __restrict__ aggp,
                 const float* __restrict__ x, const unsigned short* __restrict__ xbf,
                 const float* __restrict__ uw, const float* __restrict__ ub,
                 const float* __restrict__ lg, const float* __restrict__ lb,
                 float* __restrict__ out, int N)
{
    __shared__ unsigned short wt[128 * US];
    const int tid = threadIdx.x;
    for (int i = tid; i < 256 * 128; i += BLK) {
        int k = i >> 7, n = i & 127;
        wt[n * US + k] = f2bf(uw[i]);
    }
    __syncthreads();

    const int lane = tid & 63, w = tid >> 6;
    const int g = lane >> 4, c = lane & 15;

    float ubv[8], gv[8], bv[8];
    #pragma unroll
    for (int nt = 0; nt < 8; ++nt) {
        ubv[nt] = ub[nt * 16 + c]; gv[nt] = lg[nt * 16 + c]; bv[nt] = lb[nt * 16 + c];
    }

    const int nT = (N + 15) >> 4;
    for (int tile = blockIdx.x * WPB + w; tile < nT; tile += gridDim.x * WPB) {
        const int row = tile * 16 + c;
        const int rc  = row < N ? row : N - 1;

        const f32x4 z = {0.f, 0.f, 0.f, 0.f};
        f32x4 acc[8] = {z, z, z, z, z, z, z, z};

        #pragma unroll
        for (int kk = 0; kk < 8; ++kk) {
            bf16x8 af;
            if (kk < 4) {
                af = *(const bf16x8*)(hnb + (size_t)rc * D + kk * 32 + 8 * g);
            } else {
                if (AGGBF)
                    af = *(const bf16x8*)((const unsigned short*)aggp +
                                          (size_t)rc * D + (kk - 4) * 32 + 8 * g);
                else
                    af = cvt8((const float*)aggp + (size_t)rc * D + (kk - 4) * 32 + 8 * g);
            }
            const unsigned short* wr = &wt[c * US + kk * 32 + 8 * g];
            #pragma unroll
            for (int nt = 0; nt < 8; ++nt) {
                bf16x8 bf = *(const bf16x8*)(wr + nt * 16 * US);
                acc[nt] = __builtin_amdgcn_mfma_f32_16x16x32_bf16(af, bf, acc[nt], 0, 0, 0);
            }
        }

        float mean[4], rstd[4];
        #pragma unroll
        for (int r = 0; r < 4; ++r) {
            const int row4 = tile * 16 + 4 * g + r;
            const int r4c = row4 < N ? row4 : N - 1;
            float s = 0.f, q = 0.f;
            #pragma unroll
            for (int nt = 0; nt < 8; ++nt) {
                float xr;
                if (XBF) xr = bflo((uint32_t)xbf[(size_t)r4c * D + nt * 16 + c]);
                else     xr = x[(size_t)r4c * D + nt * 16 + c];
                float v = acc[nt][r] + ubv[nt] + xr;
                acc[nt][r] = v;
                s += v; q += v * v;
            }
            s += __shfl_xor(s, 1, 64); q += __shfl_xor(q, 1, 64);
            s += __shfl_xor(s, 2, 64); q += __shfl_xor(q, 2, 64);
            s += __shfl_xor(s, 4, 64); q += __shfl_xor(q, 4, 64);
            s += __shfl_xor(s, 8, 64); q += __shfl_xor(q, 8, 64);
            float m = s * (1.f / 128.f);
            mean[r] = m;
            rstd[r] = rsqrtf(q * (1.f / 128.f) - m * m + 1e-5f);
        }
        #pragma unroll
        for (int r = 0; r < 4; ++r) {
            const int row4 = tile * 16 + 4 * g + r;
            if (row4 < N) {
                #pragma unroll
                for (int nt = 0; nt < 8; ++nt)
                    out[(size_t)row4 * D + nt * 16 + c] =
                        (acc[nt][r] - mean[r]) * rstd[r] * gv[nt] + bv[nt];
            }
        }
    }
}

extern "C" void kernel_launch(void* const* d_in, const int* in_sizes, int n_in,
                              void* d_out, int out_size, void* d_ws, size_t ws_size,
                              hipStream_t stream)
{
    const float* x    = (const float*)d_in[0];
    const float* ea   = (const float*)d_in[1];
    const float* nw1  = (const float*)d_in[3];
    const float* nb1  = (const float*)d_in[4];
    const float* ng1  = (const float*)d_in[5];
    const float* nbe1 = (const float*)d_in[6];
    const float* nw2  = (const float*)d_in[7];
    const float* nb2  = (const float*)d_in[8];
    const float* ew1  = (const float*)d_in[9];
    const float* eb1  = (const float*)d_in[10];
    const float* eg1  = (const float*)d_in[11];
    const float* ebe1 = (const float*)d_in[12];
    const float* ew2  = (const float*)d_in[13];
    const float* eb2  = (const float*)d_in[14];
    const float* uw   = (const float*)d_in[15];
    const float* ub   = (const float*)d_in[16];
    const float* lg   = (const float*)d_in[17];
    const float* lb   = (const float*)d_in[18];
    const int*   eidx = (const int*)d_in[19];

    const int N = in_sizes[0] / D;
    const int E = in_sizes[1] / ED;

    char* base = (char*)d_ws;
    size_t off = 0;
    auto alloc = [&](size_t bytes) -> char* {
        char* p = base + off;
        off = (off + bytes + 255) & ~(size_t)255;
        return p;
    };

    // Tier A layout (CSR)
    unsigned short* hnb  = (unsigned short*)alloc((size_t)N * D * 2);
    unsigned short* aggb = (unsigned short*)alloc((size_t)N * D * 2);
    unsigned short* xbf  = (unsigned short*)alloc((size_t)N * D * 2);
    int* cnt    = (int*)alloc((size_t)N * 4);
    int* starts = (int*)alloc(((size_t)N + 1) * 4);
    int* cursor = (int*)alloc((size_t)N * 4);
    int* bsum   = (int*)alloc(1024 * 4);
    int* eids   = (int*)alloc((size_t)E * 4);
    unsigned short* h2 = (unsigned short*)alloc((size_t)E * D * 2);
    const size_t needA = off;

    const int n8 = N * D / 8;
    const int egrid = (E + 511) / 512;
    const int nb = (N + 1023) / 1024;
    const int ugrid = (((N + 15) / 16) + WPB - 1) / WPB;

    if (ws_size >= needA && nb <= 1024) {
        hipMemsetAsync(cnt, 0, (size_t)N * 4, stream);
        cvt_x_kernel<<<(n8 + 255) / 256, 256, 0, stream>>>(x, xbf, n8);
        count_kernel<<<egrid, 512, 0, stream>>>(eidx, cnt, E);
        scan_blk_kernel<<<nb, 1024, 0, stream>>>(cnt, cursor, bsum, N);
        scan_top_kernel<<<1, 1024, 0, stream>>>(bsum, nb);
        scan_add_kernel<<<nb, 1024, 0, stream>>>(cursor, bsum, starts, cursor, N, E);
        fill_kernel<<<egrid, 512, 0, stream>>>(eidx, cursor, eids, E);
        mlp_kernel<false, true, true><<<GRID, BLK, 0, stream>>>(
            x, xbf, nullptr, nullptr, nw1, nb1, ng1, nbe1, nw2, nb2, hnb, nullptr, N, E);
        mlp_kernel<true, true, true><<<GRID, BLK, 0, stream>>>(
            x, xbf, ea, eidx, ew1, eb1, eg1, ebe1, ew2, eb2, h2, nullptr, N, E);
        agg_kernel<<<(N + WPB - 1) / WPB, 512, 0, stream>>>(h2, starts, eids, aggb, N);
        upd2_kernel<true, true><<<ugrid, BLK, 0, stream>>>(
            hnb, aggb, x, xbf, uw, ub, lg, lb, (float*)d_out, N);
        return;
    }

    // Tier B layout (atomics, f32 agg)
    off = 0;
    unsigned short* hnb2 = (unsigned short*)alloc((size_t)N * D * 2);
    float* aggf = (float*)alloc((size_t)N * D * 4);
    unsigned short* xbf2 = (unsigned short*)alloc((size_t)N * D * 2);
    const size_t needB = off;

    hipMemsetAsync(aggf, 0, (size_t)N * D * 4, stream);
    if (ws_size >= needB) {
        cvt_x_kernel<<<(n8 + 255) / 256, 256, 0, stream>>>(x, xbf2, n8);
        mlp_kernel<false, true, false><<<GRID, BLK, 0, stream>>>(
            x, xbf2, nullptr, nullptr, nw1, nb1, ng1, nbe1, nw2, nb2, hnb2, nullptr, N, E);
        mlp_kernel<true, true, false><<<GRID, BLK, 0, stream>>>(
            x, xbf2, ea, eidx, ew1, eb1, eg1, ebe1, ew2, eb2, nullptr, aggf, N, E);
        upd2_kernel<false, true><<<ugrid, BLK, 0, stream>>>(
            hnb2, aggf, x, xbf2, uw, ub, lg, lb, (float*)d_out, N);
    } else {
        mlp_kernel<false, false, false><<<GRID, BLK, 0, stream>>>(
            x, nullptr, nullptr, nullptr, nw1, nb1, ng1, nbe1, nw2, nb2, hnb2, nullptr, N, E);
        mlp_kernel<true, false, false><<<GRID, BLK, 0, stream>>>(
            x, nullptr, ea, eidx, ew1, eb1, eg1, ebe1, ew2, eb2, nullptr, aggf, N, E);
        upd2_kernel<false, false><<<ugrid, BLK, 0, stream>>>(
            hnb2, aggf, x, nullptr, uw, ub, lg, lb, (float*)d_out, N);
    }
}

// Round 7
// 469.587 us; speedup vs baseline: 3.4047x; 1.0168x over previous
//
#include <hip/hip_runtime.h>
#include <stdint.h>

#define D    128
#define ED   5
#define BLK  512
#define WPB  8
#define W1S  296   // u16 stride, 16B-aligned rows
#define W2S  136
#define HS   136
#define US   264
#define GRID 256

typedef __attribute__((ext_vector_type(8))) short bf16x8;
typedef __attribute__((ext_vector_type(4))) float f32x4;

__device__ __forceinline__ unsigned short f2bf(float f) {
    union { float f; uint32_t u; } c; c.f = f;
    uint32_t r = (c.u + 0x7fffu + ((c.u >> 16) & 1u)) >> 16;
    return (unsigned short)r;
}
__device__ __forceinline__ float bflo(uint32_t u) {
    union { uint32_t u; float f; } c; c.u = u << 16; return c.f;
}
__device__ __forceinline__ float bfhi(uint32_t u) {
    union { uint32_t u; float f; } c; c.u = u & 0xffff0000u; return c.f;
}
__device__ __forceinline__ bf16x8 cvt8(const float* __restrict__ p) {
    float4 a = *(const float4*)p;
    float4 b = *(const float4*)(p + 4);
    bf16x8 r;
    r[0] = (short)f2bf(a.x); r[1] = (short)f2bf(a.y);
    r[2] = (short)f2bf(a.z); r[3] = (short)f2bf(a.w);
    r[4] = (short)f2bf(b.x); r[5] = (short)f2bf(b.y);
    r[6] = (short)f2bf(b.z); r[7] = (short)f2bf(b.w);
    return r;
}
__device__ __forceinline__ bool detect64(const int* ei) {
    return (ei[1] == 0) & (ei[3] == 0) & (ei[5] == 0) &
           (ei[7] == 0) & (ei[9] == 0) & (ei[11] == 0);
}

__global__ __launch_bounds__(256)
void cvt_x_kernel(const float* __restrict__ in, unsigned short* __restrict__ out, int n8) {
    int i = blockIdx.x * blockDim.x + threadIdx.x;
    if (i >= n8) return;
    float4 a = ((const float4*)in)[2 * i];
    float4 b = ((const float4*)in)[2 * i + 1];
    union { unsigned short s[8]; uint4 v; } p;
    p.s[0] = f2bf(a.x); p.s[1] = f2bf(a.y); p.s[2] = f2bf(a.z); p.s[3] = f2bf(a.w);
    p.s[4] = f2bf(b.x); p.s[5] = f2bf(b.y); p.s[6] = f2bf(b.z); p.s[7] = f2bf(b.w);
    ((uint4*)out)[i] = p.v;
}

// ---------------- CSR build (parallel scan, inverse-perm slot) ----------------
__global__ __launch_bounds__(512)
void count_kernel(const int* __restrict__ ei, int* __restrict__ cnt, int E) {
    const bool is64 = detect64(ei);
    int e = blockIdx.x * 512 + threadIdx.x;
    if (e >= E) return;
    int d = is64 ? ei[2 * ((size_t)E + e)] : ei[(size_t)E + e];
    atomicAdd(&cnt[d], 1);
}

__global__ __launch_bounds__(1024)
void scan_blk_kernel(const int* __restrict__ cnt, int* __restrict__ part,
                     int* __restrict__ bsum, int N) {
    __shared__ int wsum[16];
    const int tid = threadIdx.x, wave = tid >> 6, lane = tid & 63;
    const int idx = blockIdx.x * 1024 + tid;
    int v = (idx < N) ? cnt[idx] : 0;
    int s = v;
    #pragma unroll
    for (int off = 1; off < 64; off <<= 1) {
        int t = __shfl_up(s, off, 64);
        if (lane >= off) s += t;
    }
    if (lane == 63) wsum[wave] = s;
    __syncthreads();
    if (wave == 0 && lane < 16) {
        int ws_ = wsum[lane];
        #pragma unroll
        for (int off = 1; off < 16; off <<= 1) {
            int t = __shfl_up(ws_, off, 64);
            if (lane >= off) ws_ += t;
        }
        wsum[lane] = ws_;
    }
    __syncthreads();
    const int excl = ((wave == 0) ? 0 : wsum[wave - 1]) + (s - v);
    if (idx < N) part[idx] = excl;
    if (tid == 0) bsum[blockIdx.x] = wsum[15];
}

__global__ __launch_bounds__(1024)
void scan_top_kernel(int* __restrict__ bsum, int nb) {
    __shared__ int wsum[16];
    const int tid = threadIdx.x, wave = tid >> 6, lane = tid & 63;
    int v = (tid < nb) ? bsum[tid] : 0;
    int s = v;
    #pragma unroll
    for (int off = 1; off < 64; off <<= 1) {
        int t = __shfl_up(s, off, 64);
        if (lane >= off) s += t;
    }
    if (lane == 63) wsum[wave] = s;
    __syncthreads();
    if (wave == 0 && lane < 16) {
        int ws_ = wsum[lane];
        #pragma unroll
        for (int off = 1; off < 16; off <<= 1) {
            int t = __shfl_up(ws_, off, 64);
            if (lane >= off) ws_ += t;
        }
        wsum[lane] = ws_;
    }
    __syncthreads();
    const int excl = ((wave == 0) ? 0 : wsum[wave - 1]) + (s - v);
    if (tid < nb) bsum[tid] = excl;
}

__global__ __launch_bounds__(1024)
void scan_add_kernel(const int* __restrict__ part, const int* __restrict__ bsum,
                     int* __restrict__ starts, int* __restrict__ cursor,
                     int N, int E) {
    const int idx = blockIdx.x * 1024 + threadIdx.x;
    if (idx < N) {
        int v = part[idx] + bsum[blockIdx.x];
        starts[idx] = v;
        cursor[idx] = v;
    }
    if (blockIdx.x == 0 && threadIdx.x == 0) starts[N] = E;
}

// slot[e] = position of edge e in CSR (dst-grouped) order; coalesced write by e
__global__ __launch_bounds__(512)
void fill_kernel(const int* __restrict__ ei, int* __restrict__ cursor,
                 int* __restrict__ slotp, int E) {
    const bool is64 = detect64(ei);
    int e = blockIdx.x * 512 + threadIdx.x;
    if (e >= E) return;
    int d = is64 ? ei[2 * ((size_t)E + e)] : ei[(size_t)E + e];
    slotp[e] = atomicAdd(&cursor[d], 1);
}

// ---- per-dst sum over CONTIGUOUS CSR-ordered h2 rows (pure streaming) ----
__global__ __launch_bounds__(512)
void agg_kernel(const unsigned short* __restrict__ h2, const int* __restrict__ starts,
                unsigned short* __restrict__ aggb, int N) {
    const int wid = blockIdx.x * WPB + (threadIdx.x >> 6);
    if (wid >= N) return;
    const int lane = threadIdx.x & 63;
    const int s = starts[wid], t = starts[wid + 1];
    const unsigned short* p = h2 + (size_t)s * D + 2 * lane;
    const int n = t - s;
    float a0 = 0.f, a1 = 0.f, b0 = 0.f, b1 = 0.f;
    float p0 = 0.f, p1 = 0.f, q0 = 0.f, q1 = 0.f;
    int j = 0;
    for (; j + 4 <= n; j += 4) {
        uint32_t u0 = *(const uint32_t*)(p + (size_t)(j + 0) * D);
        uint32_t u1 = *(const uint32_t*)(p + (size_t)(j + 1) * D);
        uint32_t u2 = *(const uint32_t*)(p + (size_t)(j + 2) * D);
        uint32_t u3 = *(const uint32_t*)(p + (size_t)(j + 3) * D);
        a0 += bflo(u0); a1 += bfhi(u0);
        b0 += bflo(u1); b1 += bfhi(u1);
        p0 += bflo(u2); p1 += bfhi(u2);
        q0 += bflo(u3); q1 += bfhi(u3);
    }
    for (; j < n; ++j) {
        uint32_t u = *(const uint32_t*)(p + (size_t)j * D);
        a0 += bflo(u); a1 += bfhi(u);
    }
    const float r0 = (a0 + b0) + (p0 + q0);
    const float r1 = (a1 + b1) + (p1 + q1);
    uint32_t o = (uint32_t)f2bf(r0) | ((uint32_t)f2bf(r1) << 16);
    *(uint32_t*)(aggb + (size_t)wid * D + 2 * lane) = o;
}

// One wave = one 16-row m-tile, software-pipelined gathers.
// GEMM1 -> LN+ReLU -> swizzled-LDS transpose -> GEMM2.
// hb slot-swizzle: 16B slot ^= (row>>1)&7  (bank-conflict-free writes AND reads)
template<bool EDGE, bool XBF, bool CSR>
__global__ __launch_bounds__(BLK, 2)
void mlp_kernel(const float* __restrict__ x, const unsigned short* __restrict__ xbf,
                const float* __restrict__ ea, const int* __restrict__ ei,
                const int* __restrict__ slotp,
                const float* __restrict__ w1, const float* __restrict__ b1,
                const float* __restrict__ g1, const float* __restrict__ be1,
                const float* __restrict__ w2, const float* __restrict__ b2,
                unsigned short* __restrict__ hout, float* __restrict__ aggf,
                int N, int E)
{
    __shared__ unsigned short w1t[128 * W1S];
    __shared__ unsigned short w2t[128 * W2S];
    __shared__ unsigned short hb[WPB][16 * HS];

    const int tid = threadIdx.x;
    const int KROWS = EDGE ? 288 : 128;
    for (int i = tid; i < KROWS * 128; i += BLK) {
        int k = i >> 7, n = i & 127;
        float v = (!EDGE || k < (2 * D + ED)) ? w1[k * 128 + n] : 0.f;
        w1t[n * W1S + k] = f2bf(v);
    }
    for (int i = tid; i < 128 * 128; i += BLK) {
        int k = i >> 7, n = i & 127;
        w2t[n * W2S + k] = f2bf(w2[k * 128 + n]);
    }
    __syncthreads();

    bool is64 = false;
    if (EDGE) is64 = detect64(ei);

    const int lane = tid & 63, w = tid >> 6;
    const int g = lane >> 4, c = lane & 15;

    float b1v[8], g1v[8], e1v[8], b2v[8];
    #pragma unroll
    for (int nt = 0; nt < 8; ++nt) {
        b1v[nt] = b1[nt * 16 + c];  g1v[nt] = g1[nt * 16 + c];
        e1v[nt] = be1[nt * 16 + c]; b2v[nt] = b2[nt * 16 + c];
    }

    const int cnt = EDGE ? E : N;
    const int nT = (cnt + 15) >> 4;
    const int step = gridDim.x * WPB;
    unsigned short* hw = hb[w];

    // ---- software-pipeline state: indices + A-fragments of the NEXT tile ----
    int pdd = 0, prc = 0, psl = 0;
    size_t paoff = 0, pboff = 0;
    bf16x8 pf[9];

    auto loadIdx = [&](int tl) {
        const int rr = tl * 16 + c;
        const int rc = rr < cnt ? rr : cnt - 1;
        prc = rc;
        if (EDGE) {
            int s = is64 ? ei[2 * (size_t)rc]       : ei[rc];
            pdd   = is64 ? ei[2 * ((size_t)E + rc)] : ei[(size_t)E + rc];
            paoff = (size_t)s * D;
            pboff = (size_t)pdd * D;
            if (CSR) psl = slotp[rc];
        } else {
            paoff = (size_t)rc * D;
        }
    };
    auto loadFrags = [&]() {
        #pragma unroll
        for (int kk = 0; kk < (EDGE ? 8 : 4); ++kk) {
            const size_t o = (kk < 4) ? paoff + kk * 32 : pboff + (kk - 4) * 32;
            if (XBF) pf[kk] = *(const bf16x8*)(xbf + o + 8 * g);
            else     pf[kk] = cvt8(x + o + 8 * g);
        }
        if (EDGE) {
            bf16x8 t;
            #pragma unroll
            for (int j = 0; j < 8; ++j) t[j] = 0;
            if (g == 0) {
                #pragma unroll
                for (int j = 0; j < ED; ++j)
                    t[j] = (short)f2bf(ea[(size_t)prc * ED + j]);
            }
            pf[8] = t;
        }
    };

    int tile = blockIdx.x * WPB + w;
    if (tile < nT) { loadIdx(tile); loadFrags(); }

    for (; tile < nT; tile += step) {
        // consume prefetched state
        bf16x8 af[9];
        #pragma unroll
        for (int kk = 0; kk < (EDGE ? 9 : 4); ++kk) af[kk] = pf[kk];
        const int dd = pdd;
        const int sl = psl;
        const int row = tile * 16 + c;

        // issue next tile's index loads (land during GEMM1)
        const int tn = tile + step;
        loadIdx(tn < nT ? tn : tile);

        const f32x4 z = {0.f, 0.f, 0.f, 0.f};
        f32x4 acc[8] = {z, z, z, z, z, z, z, z};
        #pragma unroll
        for (int kk = 0; kk < (EDGE ? 9 : 4); ++kk) {
            const unsigned short* wr = &w1t[c * W1S + kk * 32 + 8 * g];
            #pragma unroll
            for (int nt = 0; nt < 8; ++nt) {
                bf16x8 bf = *(const bf16x8*)(wr + nt * 16 * W1S);
                acc[nt] = __builtin_amdgcn_mfma_f32_16x16x32_bf16(af[kk], bf, acc[nt], 0, 0, 0);
            }
        }

        // issue next tile's gathers (hidden under LN + transpose + GEMM2)
        loadFrags();

        // bias + LN + ReLU; C layout: col = nt*16+c, row = 4g+r
        float mean[4], rstd[4];
        #pragma unroll
        for (int r = 0; r < 4; ++r) {
            float s = 0.f, q = 0.f;
            #pragma unroll
            for (int nt = 0; nt < 8; ++nt) {
                float v = acc[nt][r] + b1v[nt];
                acc[nt][r] = v;
                s += v; q += v * v;
            }
            s += __shfl_xor(s, 1, 64); q += __shfl_xor(q, 1, 64);
            s += __shfl_xor(s, 2, 64); q += __shfl_xor(q, 2, 64);
            s += __shfl_xor(s, 4, 64); q += __shfl_xor(q, 4, 64);
            s += __shfl_xor(s, 8, 64); q += __shfl_xor(q, 8, 64);
            float m = s * (1.f / 128.f);
            float var = q * (1.f / 128.f) - m * m;
            mean[r] = m;
            rstd[r] = rsqrtf(var + 1e-5f);
        }
        // swizzled transpose write: slot(=16B unit) ^ (row>>1)&7
        #pragma unroll
        for (int nt = 0; nt < 8; ++nt) {
            #pragma unroll
            for (int r = 0; r < 4; ++r) {
                float h = fmaxf((acc[nt][r] - mean[r]) * rstd[r] * g1v[nt] + e1v[nt], 0.f);
                const int rw = 4 * g + r;
                hw[rw * HS + ((nt * 2 + (c >> 3)) ^ ((rw >> 1) & 7)) * 8 + (c & 7)] = f2bf(h);
            }
        }
        // wave-private tile: same-wave DS ordering suffices

        f32x4 acc2[8] = {z, z, z, z, z, z, z, z};
        #pragma unroll
        for (int kk = 0; kk < 4; ++kk) {
            bf16x8 hf = *(const bf16x8*)&hw[c * HS + ((4 * kk + g) ^ ((c >> 1) & 7)) * 8];
            const unsigned short* wr = &w2t[c * W2S + kk * 32 + 8 * g];
            #pragma unroll
            for (int nt = 0; nt < 8; ++nt) {
                bf16x8 bf = *(const bf16x8*)(wr + nt * 16 * W2S);
                acc2[nt] = __builtin_amdgcn_mfma_f32_16x16x32_bf16(hf, bf, acc2[nt], 0, 0, 0);
            }
        }

        if (EDGE && !CSR) {
            int dv[4];
            #pragma unroll
            for (int r = 0; r < 4; ++r) dv[r] = __shfl(dd, 4 * g + r, 64);
            #pragma unroll
            for (int r = 0; r < 4; ++r) {
                const int er = tile * 16 + 4 * g + r;
                if (er < cnt) {
                    float* dst = aggf + (size_t)dv[r] * D + c;
                    #pragma unroll
                    for (int nt = 0; nt < 8; ++nt)
                        atomicAdd(dst + nt * 16, acc2[nt][r] + b2v[nt]);
                }
            }
        } else {
            // bf16 row write via swizzled LDS transpose
            #pragma unroll
            for (int nt = 0; nt < 8; ++nt) {
                #pragma unroll
                for (int r = 0; r < 4; ++r) {
                    const int rw = 4 * g + r;
                    hw[rw * HS + ((nt * 2 + (c >> 3)) ^ ((rw >> 1) & 7)) * 8 + (c & 7)] =
                        f2bf(acc2[nt][r] + b2v[nt]);
                }
            }
            if (row < cnt) {
                // edge CSR: scatter row to its CSR-ordered position (agg streams later)
                const int orow = (EDGE && CSR) ? sl : row;
                unsigned short* dst = hout + (size_t)orow * D;
                #pragma unroll
                for (int j = 0; j < 4; ++j)
                    *(uint4*)(dst + (j * 4 + g) * 8) =
                        *(const uint4*)&hw[c * HS + ((j * 4 + g) ^ ((c >> 1) & 7)) * 8];
            }
        }
    }
}

// ---- update (MFMA): out = LN(concat(hn,agg)@uw + ub + x) ----
template<bool AGGBF, bool XBF>
__global__ __launch_bounds__(BLK, 4)
void upd2_kernel(const unsigned short* __restrict__ hnb, const void* __restrict__ aggp,
                 const float* __restrict__ x, const unsigned short* __restrict__ xbf,
                 const float* __restrict__ uw, const float* __restrict__ ub,
                 const float* __restrict__ lg, const float* __restrict__ lb,
                 float* __restrict__ out, int N)
{
    __shared__ unsigned short wt[128 * US];
    const int tid = threadIdx.x;
    for (int i = tid; i < 256 * 128; i += BLK) {
        int k = i >> 7, n = i & 127;
        wt[n * US + k] = f2bf(uw[i]);
    }
    __syncthreads();

    const int lane = tid & 63, w = tid >> 6;
    const int g = lane >> 4, c = lane & 15;

    float ubv[8], gv[8], bv[8];
    #pragma unroll
    for (int nt = 0; nt < 8; ++nt) {
        ubv[nt] = ub[nt * 16 + c]; gv[nt] = lg[nt * 16 + c]; bv[nt] = lb[nt * 16 + c];
    }

    const int nT = (N + 15) >> 4;
    for (int tile = blockIdx.x * WPB + w; tile < nT; tile += gridDim.x * WPB) {
        const int row = tile * 16 + c;
        const int rc  = row < N ? row : N - 1;

        const f32x4 z = {0.f, 0.f, 0.f, 0.f};
        f32x4 acc[8] = {z, z, z, z, z, z, z, z};

        #pragma unroll
        for (int kk = 0; kk < 8; ++kk) {
            bf16x8 af;
            if (kk < 4) {
                af = *(const bf16x8*)(hnb + (size_t)rc * D + kk * 32 + 8 * g);
            } else {
                if (AGGBF)
                    af = *(const bf16x8*)((const unsigned short*)aggp +
                                          (size_t)rc * D + (kk - 4) * 32 + 8 * g);
                else
                    af = cvt8((const float*)aggp + (size_t)rc * D + (kk - 4) * 32 + 8 * g);
            }
            const unsigned short* wr = &wt[c * US + kk * 32 + 8 * g];
            #pragma unroll
            for (int nt = 0; nt < 8; ++nt) {
                bf16x8 bf = *(const bf16x8*)(wr + nt * 16 * US);
                acc[nt] = __builtin_amdgcn_mfma_f32_16x16x32_bf16(af, bf, acc[nt], 0, 0, 0);
            }
        }

        float mean[4], rstd[4];
        #pragma unroll
        for (int r = 0; r < 4; ++r) {
            const int row4 = tile * 16 + 4 * g + r;
            const int r4c = row4 < N ? row4 : N - 1;
            float s = 0.f, q = 0.f;
            #pragma unroll
            for (int nt = 0; nt < 8; ++nt) {
                float xr;
                if (XBF) xr = bflo((uint32_t)xbf[(size_t)r4c * D + nt * 16 + c]);
                else     xr = x[(size_t)r4c * D + nt * 16 + c];
                float v = acc[nt][r] + ubv[nt] + xr;
                acc[nt][r] = v;
                s += v; q += v * v;
            }
            s += __shfl_xor(s, 1, 64); q += __shfl_xor(q, 1, 64);
            s += __shfl_xor(s, 2, 64); q += __shfl_xor(q, 2, 64);
            s += __shfl_xor(s, 4, 64); q += __shfl_xor(q, 4, 64);
            s += __shfl_xor(s, 8, 64); q += __shfl_xor(q, 8, 64);
            float m = s * (1.f / 128.f);
            mean[r] = m;
            rstd[r] = rsqrtf(q * (1.f / 128.f) - m * m + 1e-5f);
        }
        #pragma unroll
        for (int r = 0; r < 4; ++r) {
            const int row4 = tile * 16 + 4 * g + r;
            if (row4 < N) {
                #pragma unroll
                for (int nt = 0; nt < 8; ++nt)
                    out[(size_t)row4 * D + nt * 16 + c] =
                        (acc[nt][r] - mean[r]) * rstd[r] * gv[nt] + bv[nt];
            }
        }
    }
}

extern "C" void kernel_launch(void* const* d_in, const int* in_sizes, int n_in,
                              void* d_out, int out_size, void* d_ws, size_t ws_size,
                              hipStream_t stream)
{
    const float* x    = (const float*)d_in[0];
    const float* ea   = (const float*)d_in[1];
    const float* nw1  = (const float*)d_in[3];
    const float* nb1  = (const float*)d_in[4];
    const float* ng1  = (const float*)d_in[5];
    const float* nbe1 = (const float*)d_in[6];
    const float* nw2  = (const float*)d_in[7];
    const float* nb2  = (const float*)d_in[8];
    const float* ew1  = (const float*)d_in[9];
    const float* eb1  = (const float*)d_in[10];
    const float* eg1  = (const float*)d_in[11];
    const float* ebe1 = (const float*)d_in[12];
    const float* ew2  = (const float*)d_in[13];
    const float* eb2  = (const float*)d_in[14];
    const float* uw   = (const float*)d_in[15];
    const float* ub   = (const float*)d_in[16];
    const float* lg   = (const float*)d_in[17];
    const float* lb   = (const float*)d_in[18];
    const int*   eidx = (const int*)d_in[19];

    const int N = in_sizes[0] / D;
    const int E = in_sizes[1] / ED;

    char* base = (char*)d_ws;
    size_t off = 0;
    auto alloc = [&](size_t bytes) -> char* {
        char* p = base + off;
        off = (off + bytes + 255) & ~(size_t)255;
        return p;
    };

    // Tier A layout (CSR-slot)
    unsigned short* hnb  = (unsigned short*)alloc((size_t)N * D * 2);
    unsigned short* aggb = (unsigned short*)alloc((size_t)N * D * 2);
    unsigned short* xbf  = (unsigned short*)alloc((size_t)N * D * 2);
    int* cnt    = (int*)alloc((size_t)N * 4);
    int* starts = (int*)alloc(((size_t)N + 1) * 4);
    int* cursor = (int*)alloc((size_t)N * 4);
    int* bsum   = (int*)alloc(1024 * 4);
    int* slotA  = (int*)alloc((size_t)E * 4);
    unsigned short* h2 = (unsigned short*)alloc((size_t)E * D * 2);
    const size_t needA = off;

    const int n8 = N * D / 8;
    const int egrid = (E + 511) / 512;
    const int nb = (N + 1023) / 1024;
    const int ugrid = (((N + 15) / 16) + WPB - 1) / WPB;

    if (ws_size >= needA && nb <= 1024) {
        hipMemsetAsync(cnt, 0, (size_t)N * 4, stream);
        cvt_x_kernel<<<(n8 + 255) / 256, 256, 0, stream>>>(x, xbf, n8);
        count_kernel<<<egrid, 512, 0, stream>>>(eidx, cnt, E);
        scan_blk_kernel<<<nb, 1024, 0, stream>>>(cnt, cursor, bsum, N);
        scan_top_kernel<<<1, 1024, 0, stream>>>(bsum, nb);
        scan_add_kernel<<<nb, 1024, 0, stream>>>(cursor, bsum, starts, cursor, N, E);
        fill_kernel<<<egrid, 512, 0, stream>>>(eidx, cursor, slotA, E);
        mlp_kernel<false, true, true><<<GRID, BLK, 0, stream>>>(
            x, xbf, nullptr, nullptr, nullptr, nw1, nb1, ng1, nbe1, nw2, nb2,
            hnb, nullptr, N, E);
        mlp_kernel<true, true, true><<<GRID, BLK, 0, stream>>>(
            x, xbf, ea, eidx, slotA, ew1, eb1, eg1, ebe1, ew2, eb2,
            h2, nullptr, N, E);
        agg_kernel<<<(N + WPB - 1) / WPB, 512, 0, stream>>>(h2, starts, aggb, N);
        upd2_kernel<true, true><<<ugrid, BLK, 0, stream>>>(
            hnb, aggb, x, xbf, uw, ub, lg, lb, (float*)d_out, N);
        return;
    }

    // Tier B layout (atomics, f32 agg)
    off = 0;
    unsigned short* hnb2 = (unsigned short*)alloc((size_t)N * D * 2);
    float* aggf = (float*)alloc((size_t)N * D * 4);
    unsigned short* xbf2 = (unsigned short*)alloc((size_t)N * D * 2);
    const size_t needB = off;

    hipMemsetAsync(aggf, 0, (size_t)N * D * 4, stream);
    if (ws_size >= needB) {
        cvt_x_kernel<<<(n8 + 255) / 256, 256, 0, stream>>>(x, xbf2, n8);
        mlp_kernel<false, true, false><<<GRID, BLK, 0, stream>>>(
            x, xbf2, nullptr, nullptr, nullptr, nw1, nb1, ng1, nbe1, nw2, nb2,
            hnb2, nullptr, N, E);
        mlp_kernel<true, true, false><<<GRID, BLK, 0, stream>>>(
            x, xbf2, ea, eidx, nullptr, ew1, eb1, eg1, ebe1, ew2, eb2,
            nullptr, aggf, N, E);
        upd2_kernel<false, true><<<ugrid, BLK, 0, stream>>>(
            hnb2, aggf, x, xbf2, uw, ub, lg, lb, (float*)d_out, N);
    } else {
        mlp_kernel<false, false, false><<<GRID, BLK, 0, stream>>>(
            x, nullptr, nullptr, nullptr, nullptr, nw1, nb1, ng1, nbe1, nw2, nb2,
            hnb2, nullptr, N, E);
        mlp_kernel<true, false, false><<<GRID, BLK, 0, stream>>>(
            x, nullptr, ea, eidx, nullptr, ew1, eb1, eg1, ebe1, ew2, eb2,
            nullptr, aggf, N, E);
        upd2_kernel<false, false><<<ugrid, BLK, 0, stream>>>(
            hnb2, aggf, x, nullptr, uw, ub, lg, lb, (float*)d_out, N);
    }
}